// Round 3
// baseline (2768.736 us; speedup 1.0000x reference)
//
#include <hip/hip_runtime.h>
#include <math.h>
#include <stdint.h>

#define D_ 768
#define E_ 8
#define K_ 2
#define HFF_ 2048

typedef _Float16 h16;
typedef _Float16 h8 __attribute__((ext_vector_type(8)));
typedef float f32x4 __attribute__((ext_vector_type(4)));

__device__ __forceinline__ float wred(float v){
#pragma unroll
  for (int o = 32; o; o >>= 1) v += __shfl_xor(v, o);
  return v;
}
__device__ __forceinline__ int wredi(int v){
#pragma unroll
  for (int o = 32; o; o >>= 1) v += __shfl_xor(v, o);
  return v;
}
__device__ __forceinline__ float gelu_f(float v){
  return 0.5f * v * (1.f + erff(v * 0.70710678118654752f));
}
__device__ __forceinline__ float silu_f(float v){
  return v / (1.f + expf(-v));
}
__device__ __forceinline__ h8 cvt8(float4 u0, float4 u1, float sc){
  h8 t;
  t[0] = (h16)(u0.x * sc); t[1] = (h16)(u0.y * sc);
  t[2] = (h16)(u0.z * sc); t[3] = (h16)(u0.w * sc);
  t[4] = (h16)(u1.x * sc); t[5] = (h16)(u1.y * sc);
  t[6] = (h16)(u1.z * sc); t[7] = (h16)(u1.w * sc);
  return t;
}

// ---------------- router: logits, top2, softmaxes, per-block partial stats ----------------
__global__ void router_k(const float* __restrict__ x, const float* __restrict__ gw,
                         float* __restrict__ partials, int* __restrict__ pcounts,
                         float* __restrict__ prio, float* __restrict__ tkprob,
                         int* __restrict__ te, float* __restrict__ out_topk, int N)
{
  int wid = threadIdx.x >> 6;
  int lane = threadIdx.x & 63;
  int n = blockIdx.x * 4 + wid;
  __shared__ float lp[4][17];
  __shared__ int lc[4][8];
  float acc[E_];
#pragma unroll
  for (int e = 0; e < E_; e++) acc[e] = 0.f;
  if (n < N) {
    const float* xr = x + (size_t)n * D_;
    for (int c = lane; c < D_; c += 64) {
      float xv = xr[c];
#pragma unroll
      for (int e = 0; e < E_; e++) acc[e] += xv * gw[e * D_ + c];
    }
  }
#pragma unroll
  for (int e = 0; e < E_; e++) acc[e] = wred(acc[e]);
  if (lane == 0) {
    if (n < N) {
      int i0 = 0;
#pragma unroll
      for (int e = 1; e < E_; e++) if (acc[e] > acc[i0]) i0 = e;
      int i1 = -1; float b1 = -3.0e38f;
#pragma unroll
      for (int e = 0; e < E_; e++) if (e != i0 && acc[e] > b1) { b1 = acc[e]; i1 = e; }
      float v0 = acc[i0], v1 = acc[i1];
      float m2 = fmaxf(v0, v1);
      float e0 = expf(v0 - m2), e1 = expf(v1 - m2);
      float p0 = e0 / (e0 + e1), p1 = e1 / (e0 + e1);
      float mx = acc[0];
#pragma unroll
      for (int e = 1; e < E_; e++) mx = fmaxf(mx, acc[e]);
      float se = 0.f;
#pragma unroll
      for (int e = 0; e < E_; e++) se += expf(acc[e] - mx);
      float z = mx + logf(se);
      float inv = 1.f / se;
#pragma unroll
      for (int e = 0; e < E_; e++) lp[wid][e] = expf(acc[e] - mx) * inv;
#pragma unroll
      for (int e = 0; e < E_; e++) lp[wid][8 + e] = (e == i0) ? p0 : ((e == i1) ? p1 : 0.f);
      lp[wid][16] = z * z;
#pragma unroll
      for (int e = 0; e < E_; e++) lc[wid][e] = (e == i0) + (e == i1);
      te[n * 2] = i0; te[n * 2 + 1] = i1;
      prio[n * 2] = v0; prio[n * 2 + 1] = v1;
      tkprob[n * 2] = p0; tkprob[n * 2 + 1] = p1;
      out_topk[n * 2] = (float)i0; out_topk[n * 2 + 1] = (float)i1;
    } else {
      for (int t = 0; t < 17; t++) lp[wid][t] = 0.f;
      for (int e = 0; e < E_; e++) lc[wid][e] = 0;
    }
  }
  __syncthreads();
  int tid = threadIdx.x;
  if (tid < 17)
    partials[(size_t)blockIdx.x * 17 + tid] = lp[0][tid] + lp[1][tid] + lp[2][tid] + lp[3][tid];
  if (tid >= 32 && tid < 40) {
    int e = tid - 32;
    pcounts[(size_t)blockIdx.x * 8 + e] = lc[0][e] + lc[1][e] + lc[2][e] + lc[3][e];
  }
}

// ---------------- stats: parallel reduce partials, counts->starts/rows, aux ----------------
__global__ void stats_k(const float* __restrict__ partials, const int* __restrict__ pcounts,
                        int NB, int* __restrict__ counts, int* __restrict__ starts,
                        int* __restrict__ rows_e, int* __restrict__ ctr,
                        float* __restrict__ aux_out, int N, int C)
{
  __shared__ float ssum[17];
  __shared__ int scnt[8];
  int wave = threadIdx.x >> 6, lane = threadIdx.x & 63;
  for (int v = wave; v < 17; v += 4) {
    float s = 0.f;
    for (int b = lane; b < NB; b += 64) s += partials[(size_t)b * 17 + v];
    s = wred(s);
    if (lane == 0) ssum[v] = s;
  }
  for (int e = wave; e < 8; e += 4) {
    int c = 0;
    for (int b = lane; b < NB; b += 64) c += pcounts[(size_t)b * 8 + e];
    c = wredi(c);
    if (lane == 0) scnt[e] = c;
  }
  __syncthreads();
  if (threadIdx.x == 0) {
    int st = 0, kept = 0;
    float bal = 0.f;
    for (int e = 0; e < E_; e++) {
      counts[e] = scnt[e]; starts[e] = st; st += scnt[e];
      int r = scnt[e] < C ? scnt[e] : C;
      rows_e[e] = r; kept += r;
      bal += (ssum[e] / N) * (ssum[8 + e] / N);
      ctr[e] = 0;
    }
    int NK = N * K_;
    float aux = 0.01f * bal * (float)E_ + 0.001f * (ssum[16] / N)
              + 0.001f * (1.f - (float)kept / (float)NK);
    aux_out[0] = aux;
  }
}

// ---------------- rank/slot assignment ----------------
__global__ void rank_k(const int* __restrict__ te, const float* __restrict__ prio,
                       const int* __restrict__ counts, const int* __restrict__ starts,
                       int* __restrict__ ctr, int* __restrict__ rowmap,
                       int* __restrict__ keep_nk, int NK, int C)
{
  int i = blockIdx.x * 256 + threadIdx.x;
  if (i >= NK) return;
  int e = te[i];
  int cnt = counts[e];
  int pos;
  if (cnt <= C) {
    pos = atomicAdd(&ctr[e], 1);  // within-expert order unobservable when nothing drops
  } else {
    float p = prio[i]; int r = 0;
    for (int j = 0; j < NK; j++) {
      if (te[j] == e) { float pj = prio[j]; r += (pj > p) || (pj == p && j < i); }
    }
    pos = r;
  }
  int kp = pos < C ? 1 : 0;
  keep_nk[i] = kp;
  if (kp) rowmap[starts[e] + pos] = i;
}

// ---------------- tokens init: zeros + mediator in slot 2 (fp32 + fp16) ----------------
__global__ void tokinit_k(float* __restrict__ tokens, h16* __restrict__ tokh,
                          const float* __restrict__ med, int total)
{
  for (int idx = blockIdx.x * 256 + threadIdx.x; idx < total; idx += gridDim.x * 256) {
    int r = idx % (3 * D_);
    float v = (r >= 2 * D_) ? med[r - 2 * D_] : 0.f;
    tokens[idx] = v; tokh[idx] = (h16)v;
  }
}

// =====================================================================================
// MFMA GEMM core: C(M,N) = A(M,K)@B(N,K)^T. A fp16 (row stride lda), B fp32 cvt-on-stage.
// 128x128 tile, BK=64, 4 waves (2x2), each wave 4x4 frags of 16x16x32.
// LDS fragment-ordered: unit u (16 rows x 32 k) at u*512 halves; lane l -> +l*8.
// EPI: 0 = +bias -> C16          (qkv)
//      1 = C32 += acc + bias     (out-proj residual into tokens)
//      2 = gelu -> C16           (ffn h1)
//      3 = t=acc+C32; C32=t; C16=t  (ffn out + resid, tokens & tokh)
//      4 = plain -> C32          (final out-proj)
// =====================================================================================
template<int EPI>
__global__ __launch_bounds__(256, 2) void mgemm_k(
    const h16* __restrict__ A, int lda, const float* __restrict__ Bf,
    const float* __restrict__ bias, float* C32, h16* C16, int M, int N, int K)
{
  __shared__ __align__(16) h16 ls[16384];
  const int tid = threadIdx.x;
  const int lane = tid & 63, wave = tid >> 6;
  const int wm = wave >> 1, wn = wave & 1;
  const int lr = lane & 15, lk = lane >> 4;
  const int m0 = blockIdx.y * 128, n0 = blockIdx.x * 128;

  f32x4 acc[4][4];
#pragma unroll
  for (int i = 0; i < 4; ++i)
#pragma unroll
    for (int j = 0; j < 4; ++j) acc[i][j] = f32x4{0.f, 0.f, 0.f, 0.f};

  const int ldsbase = (wave < 2) ? wave * 4096 : 8192 + (wave - 2) * 4096;
  const int koff = (wave & 1) * 32 + lk * 8;
  size_t srow[8];
  if (wave < 2) {
#pragma unroll
    for (int j = 0; j < 8; ++j) srow[j] = (size_t)(m0 + j * 16 + lr) * (size_t)lda;
  } else {
#pragma unroll
    for (int j = 0; j < 8; ++j) srow[j] = (size_t)(n0 + j * 16 + lr) * (size_t)K;
  }

  const int nkt = K >> 6;
  for (int kt = 0; kt < nkt; ++kt) {
    const int kb = kt * 64 + koff;
    h8 tmp[8];
    if (wave < 2) {
#pragma unroll
      for (int j = 0; j < 8; ++j) tmp[j] = *(const h8*)(A + srow[j] + kb);
    } else {
#pragma unroll
      for (int j = 0; j < 8; ++j) {
        float4 u0 = *(const float4*)(Bf + srow[j] + kb);
        float4 u1 = *(const float4*)(Bf + srow[j] + kb + 4);
        tmp[j] = cvt8(u0, u1, 1.f);
      }
    }
    __syncthreads();
#pragma unroll
    for (int j = 0; j < 8; ++j) *(h8*)&ls[ldsbase + j * 512 + lane * 8] = tmp[j];
    __syncthreads();
#pragma unroll
    for (int kc = 0; kc < 2; ++kc) {
      h8 af[4], bf[4];
#pragma unroll
      for (int i = 0; i < 4; ++i) af[i] = *(const h8*)&ls[(kc * 8 + wm * 4 + i) * 512 + lane * 8];
#pragma unroll
      for (int j = 0; j < 4; ++j) bf[j] = *(const h8*)&ls[8192 + (kc * 8 + wn * 4 + j) * 512 + lane * 8];
#pragma unroll
      for (int i = 0; i < 4; ++i)
#pragma unroll
        for (int j = 0; j < 4; ++j)
          acc[i][j] = __builtin_amdgcn_mfma_f32_16x16x32_f16(af[i], bf[j], acc[i][j], 0, 0, 0);
    }
  }

#pragma unroll
  for (int i = 0; i < 4; ++i) {
    const int row0 = m0 + (wm * 4 + i) * 16 + lk * 4;
#pragma unroll
    for (int j = 0; j < 4; ++j) {
      const int col = n0 + (wn * 4 + j) * 16 + lr;
      const float bv = (EPI == 0 || EPI == 1) ? bias[col] : 0.f;
#pragma unroll
      for (int r = 0; r < 4; ++r) {
        const size_t o = (size_t)(row0 + r) * N + col;
        const float v = acc[i][j][r];
        if (EPI == 0)      { C16[o] = (h16)(v + bv); }
        else if (EPI == 1) { C32[o] += v + bv; }
        else if (EPI == 2) { C16[o] = (h16)gelu_f(v); }
        else if (EPI == 3) { float t = v + C32[o]; C32[o] = t; C16[o] = (h16)t; }
        else               { C32[o] = v; }
      }
    }
  }
}

// ---------------- expert GEMM1: act = silu(2x W13g^T) * (2x W13u^T), fp32 in, gather ---------
// B units j: cg=j>>1 (out colgroup), half=j&1 (0 gate / 1 up)
__global__ __launch_bounds__(256, 2) void egemm1_k(
    const float* __restrict__ x, const float* __restrict__ w13,
    const int* __restrict__ rowmap, const int* __restrict__ starts,
    const int* __restrict__ rows_e, h16* __restrict__ acth)
{
  const int e = blockIdx.z;
  const int rows = rows_e[e], st = starts[e];
  const int r0 = blockIdx.y * 128;
  if (r0 >= rows) return;
  const int h0 = blockIdx.x * 64;

  __shared__ __align__(16) h16 ls[16384];
  const int tid = threadIdx.x;
  const int lane = tid & 63, wave = tid >> 6;
  const int wm = wave >> 1, wn = wave & 1;
  const int lr = lane & 15, lk = lane >> 4;

  f32x4 acc[4][4];
#pragma unroll
  for (int i = 0; i < 4; ++i)
#pragma unroll
    for (int j = 0; j < 4; ++j) acc[i][j] = f32x4{0.f, 0.f, 0.f, 0.f};

  const int ldsbase = (wave < 2) ? wave * 4096 : 8192 + (wave - 2) * 4096;
  const int koff = (wave & 1) * 32 + lk * 8;
  const float ascale = (wave < 2) ? 2.f : 1.f;
  const float* srcb = (wave < 2) ? x : w13;
  size_t srow[8];
  if (wave < 2) {
#pragma unroll
    for (int j = 0; j < 8; ++j) {
      int r = r0 + j * 16 + lr; if (r >= rows) r = rows - 1;
      srow[j] = (size_t)(rowmap[st + r] >> 1) * D_;
    }
  } else {
#pragma unroll
    for (int j = 0; j < 8; ++j) {
      int cg = j >> 1, half = j & 1;
      srow[j] = ((size_t)e * 4096 + half * 2048 + h0 + cg * 16 + lr) * D_;
    }
  }

  for (int kt = 0; kt < D_ / 64; ++kt) {
    const int kb = kt * 64 + koff;
    h8 tmp[8];
#pragma unroll
    for (int j = 0; j < 8; ++j) {
      float4 u0 = *(const float4*)(srcb + srow[j] + kb);
      float4 u1 = *(const float4*)(srcb + srow[j] + kb + 4);
      tmp[j] = cvt8(u0, u1, ascale);
    }
    __syncthreads();
#pragma unroll
    for (int j = 0; j < 8; ++j) *(h8*)&ls[ldsbase + j * 512 + lane * 8] = tmp[j];
    __syncthreads();
#pragma unroll
    for (int kc = 0; kc < 2; ++kc) {
      h8 af[4], bf[4];
#pragma unroll
      for (int i = 0; i < 4; ++i) af[i] = *(const h8*)&ls[(kc * 8 + wm * 4 + i) * 512 + lane * 8];
#pragma unroll
      for (int j = 0; j < 4; ++j) bf[j] = *(const h8*)&ls[8192 + (kc * 8 + wn * 4 + j) * 512 + lane * 8];
#pragma unroll
      for (int i = 0; i < 4; ++i)
#pragma unroll
        for (int j = 0; j < 4; ++j)
          acc[i][j] = __builtin_amdgcn_mfma_f32_16x16x32_f16(af[i], bf[j], acc[i][j], 0, 0, 0);
    }
  }

#pragma unroll
  for (int i = 0; i < 4; ++i) {
    const int rloc = r0 + (wm * 4 + i) * 16 + lk * 4;
#pragma unroll
    for (int jc = 0; jc < 2; ++jc) {
      const int col = h0 + (wn * 2 + jc) * 16 + lr;
#pragma unroll
      for (int r = 0; r < 4; ++r) {
        const int rr = rloc + r;
        if (rr < rows) {
          float g = acc[i][2 * jc][r], u = acc[i][2 * jc + 1][r];
          acth[(size_t)(st + rr) * HFF_ + col] = (h16)(silu_f(g) * u);
        }
      }
    }
  }
}

// ---------------- expert GEMM2: tokens[t,l] = x[t] + act @ w2[e]^T (scatter) ----------------
__global__ __launch_bounds__(256, 2) void egemm2_k(
    const h16* __restrict__ acth, const float* __restrict__ w2,
    const int* __restrict__ rowmap, const int* __restrict__ starts,
    const int* __restrict__ rows_e, const float* __restrict__ x,
    float* __restrict__ tokens, h16* __restrict__ tokh)
{
  const int e = blockIdx.z;
  const int rows = rows_e[e], st = starts[e];
  const int r0 = blockIdx.y * 128;
  if (r0 >= rows) return;
  const int n0 = blockIdx.x * 128;

  __shared__ __align__(16) h16 ls[16384];
  const int tid = threadIdx.x;
  const int lane = tid & 63, wave = tid >> 6;
  const int wm = wave >> 1, wn = wave & 1;
  const int lr = lane & 15, lk = lane >> 4;

  f32x4 acc[4][4];
#pragma unroll
  for (int i = 0; i < 4; ++i)
#pragma unroll
    for (int j = 0; j < 4; ++j) acc[i][j] = f32x4{0.f, 0.f, 0.f, 0.f};

  const int ldsbase = (wave < 2) ? wave * 4096 : 8192 + (wave - 2) * 4096;
  const int koff = (wave & 1) * 32 + lk * 8;
  size_t srow[8];
  if (wave < 2) {
#pragma unroll
    for (int j = 0; j < 8; ++j) {
      int r = r0 + j * 16 + lr; if (r >= rows) r = rows - 1;
      srow[j] = (size_t)(st + r) * HFF_;
    }
  } else {
#pragma unroll
    for (int j = 0; j < 8; ++j)
      srow[j] = ((size_t)e * D_ + n0 + j * 16 + lr) * HFF_;
  }

  for (int kt = 0; kt < HFF_ / 64; ++kt) {
    const int kb = kt * 64 + koff;
    h8 tmp[8];
    if (wave < 2) {
#pragma unroll
      for (int j = 0; j < 8; ++j) tmp[j] = *(const h8*)(acth + srow[j] + kb);
    } else {
#pragma unroll
      for (int j = 0; j < 8; ++j) {
        float4 u0 = *(const float4*)(w2 + srow[j] + kb);
        float4 u1 = *(const float4*)(w2 + srow[j] + kb + 4);
        tmp[j] = cvt8(u0, u1, 1.f);
      }
    }
    __syncthreads();
#pragma unroll
    for (int j = 0; j < 8; ++j) *(h8*)&ls[ldsbase + j * 512 + lane * 8] = tmp[j];
    __syncthreads();
#pragma unroll
    for (int kc = 0; kc < 2; ++kc) {
      h8 af[4], bf[4];
#pragma unroll
      for (int i = 0; i < 4; ++i) af[i] = *(const h8*)&ls[(kc * 8 + wm * 4 + i) * 512 + lane * 8];
#pragma unroll
      for (int j = 0; j < 4; ++j) bf[j] = *(const h8*)&ls[8192 + (kc * 8 + wn * 4 + j) * 512 + lane * 8];
#pragma unroll
      for (int i = 0; i < 4; ++i)
#pragma unroll
        for (int j = 0; j < 4; ++j)
          acc[i][j] = __builtin_amdgcn_mfma_f32_16x16x32_f16(af[i], bf[j], acc[i][j], 0, 0, 0);
    }
  }

#pragma unroll
  for (int i = 0; i < 4; ++i) {
    const int rloc = r0 + (wm * 4 + i) * 16 + lk * 4;
#pragma unroll
    for (int j = 0; j < 4; ++j) {
      const int col = n0 + (wn * 4 + j) * 16 + lr;
#pragma unroll
      for (int r = 0; r < 4; ++r) {
        const int rr = rloc + r;
        if (rr < rows) {
          int item = rowmap[st + rr];
          int t = item >> 1, l = item & 1;
          size_t o = ((size_t)t * 3 + l) * D_ + col;
          float v = acc[i][j][r] + x[(size_t)t * D_ + col];
          tokens[o] = v; tokh[o] = (h16)v;
        }
      }
    }
  }
}

// ---------------- attention over L=3 tokens, IN-PLACE into q-slots of qkv ----------------
// NOTE: qkv deliberately NOT __restrict__ (reads and writes alias). All reads
// complete into registers before any write; per-thread address sets are disjoint
// across threads.
__global__ void attn_k(h16* qkv, const int* __restrict__ keep_nk, int N)
{
  int n = blockIdx.x;
  int h = threadIdx.y, lane = threadIdx.x;
  h16* base = qkv + (size_t)n * 3 * 2304;
  float qr[3][3], kr[3][3], vr[3][3];
#pragma unroll
  for (int l2 = 0; l2 < 3; l2++) {
    const h16* row = base + l2 * 2304 + h * 192;
#pragma unroll
    for (int c = 0; c < 3; c++) {
      qr[l2][c] = (float)row[c * 64 + lane];
      kr[l2][c] = (float)row[768 + c * 64 + lane];
      vr[l2][c] = (float)row[1536 + c * 64 + lane];
    }
  }
  const float scale = 0.07216878364870323f; // 1/sqrt(192)
  float bj0 = keep_nk[n * 2] ? 0.f : -1e9f;
  float bj1 = keep_nk[n * 2 + 1] ? 0.f : -1e9f;
  float a[3][3];
#pragma unroll
  for (int i2 = 0; i2 < 3; i2++) {
    float s0 = wred(qr[i2][0] * kr[0][0] + qr[i2][1] * kr[0][1] + qr[i2][2] * kr[0][2]) * scale + bj0;
    float s1 = wred(qr[i2][0] * kr[1][0] + qr[i2][1] * kr[1][1] + qr[i2][2] * kr[1][2]) * scale + bj1;
    float s2 = wred(qr[i2][0] * kr[2][0] + qr[i2][1] * kr[2][1] + qr[i2][2] * kr[2][2]) * scale;
    float m = fmaxf(s0, fmaxf(s1, s2));
    float e0 = expf(s0 - m), e1 = expf(s1 - m), e2 = expf(s2 - m);
    float inv = 1.f / (e0 + e1 + e2);
    a[i2][0] = e0 * inv; a[i2][1] = e1 * inv; a[i2][2] = e2 * inv;
  }
#pragma unroll
  for (int i2 = 0; i2 < 3; i2++) {
    h16* dst = base + i2 * 2304 + h * 192;
#pragma unroll
    for (int c = 0; c < 3; c++)
      dst[c * 64 + lane] = (h16)(a[i2][0] * vr[0][c] + a[i2][1] * vr[1][c] + a[i2][2] * vr[2][c]);
  }
}

// ---------------- RMSNorm 1: tokens = rms(tokens)*w (fp32 in-place) ----------------
__global__ void rms1_k(float* tokens, const float* __restrict__ w)
{
  int row = blockIdx.x, tid = threadIdx.x;
  float* s = tokens + (size_t)row * D_;
  float v0 = s[tid], v1 = s[tid + 256], v2 = s[tid + 512];
  float ss = v0 * v0 + v1 * v1 + v2 * v2;
  __shared__ float red[4];
  float wsum = wred(ss);
  if ((tid & 63) == 0) red[tid >> 6] = wsum;
  __syncthreads();
  float tot = red[0] + red[1] + red[2] + red[3];
  float r = 1.f / sqrtf(tot * (1.f / 768.f) + 1e-6f);
  s[tid]       = v0 * r * w[tid];
  s[tid + 256] = v1 * r * w[tid + 256];
  s[tid + 512] = v2 * r * w[tid + 512];
}

// ---------------- RMSNorm 2: nrmh = (fp16) rms(tokens)*w ----------------
__global__ void rms2_k(const float* __restrict__ tokens, const float* __restrict__ w,
                       h16* __restrict__ d)
{
  int row = blockIdx.x, tid = threadIdx.x;
  const float* s = tokens + (size_t)row * D_;
  float v0 = s[tid], v1 = s[tid + 256], v2 = s[tid + 512];
  float ss = v0 * v0 + v1 * v1 + v2 * v2;
  __shared__ float red[4];
  float wsum = wred(ss);
  if ((tid & 63) == 0) red[tid >> 6] = wsum;
  __syncthreads();
  float tot = red[0] + red[1] + red[2] + red[3];
  float r = 1.f / sqrtf(tot * (1.f / 768.f) + 1e-6f);
  h16* dd = d + (size_t)row * D_;
  dd[tid]       = (h16)(v0 * r * w[tid]);
  dd[tid + 256] = (h16)(v1 * r * w[tid + 256]);
  dd[tid + 512] = (h16)(v2 * r * w[tid + 512]);
}

// ---------------- final fuse: fusedh = (fp16)( g*med + (1-g)*weighted-agg ) ----------------
__global__ void fuse_k(const float* __restrict__ tokens, const float* __restrict__ tkprob,
                       const int* __restrict__ keep_nk, const float* __restrict__ fw,
                       const float* __restrict__ fb, h16* __restrict__ out)
{
  int n = blockIdx.x; int tid = threadIdx.x;
  const float* t0 = tokens + ((size_t)n * 3 + 0) * D_;
  const float* t1 = tokens + ((size_t)n * 3 + 1) * D_;
  const float* md = tokens + ((size_t)n * 3 + 2) * D_;
  float p = md[tid] * fw[tid] + md[tid + 256] * fw[tid + 256] + md[tid + 512] * fw[tid + 512];
  __shared__ float red[4];
  float wsum = wred(p);
  if ((tid & 63) == 0) red[tid >> 6] = wsum;
  __syncthreads();
  float dot = red[0] + red[1] + red[2] + red[3];
  float g = 1.f / (1.f + expf(-(dot + fb[0])));
  float tp0 = keep_nk[n * 2] ? tkprob[n * 2] : 0.f;
  float tp1 = keep_nk[n * 2 + 1] ? tkprob[n * 2 + 1] : 0.f;
  float den = tp0 + tp1;
  float w0 = den > 0.f ? tp0 / den : 0.f;
  float w1 = den > 0.f ? tp1 / den : 0.f;
  h16* d = out + (size_t)n * D_;
#pragma unroll
  for (int c3 = 0; c3 < 3; c3++) {
    int c = tid + c3 * 256;
    d[c] = (h16)(g * md[c] + (1.f - g) * (w0 * t0[c] + w1 * t1[c]));
  }
}

extern "C" void kernel_launch(void* const* d_in, const int* in_sizes, int n_in,
                              void* d_out, int out_size, void* d_ws, size_t ws_size,
                              hipStream_t stream) {
  const float* x         = (const float*)d_in[0];
  const float* gate_w    = (const float*)d_in[1];
  const float* w13       = (const float*)d_in[2];
  const float* w2        = (const float*)d_in[3];
  const float* in_proj_w = (const float*)d_in[4];
  const float* in_proj_b = (const float*)d_in[5];
  const float* out_w     = (const float*)d_in[6];
  const float* out_b     = (const float*)d_in[7];
  const float* norm1_w   = (const float*)d_in[8];
  const float* norm2_w   = (const float*)d_in[9];
  const float* ffn_w1    = (const float*)d_in[10];
  const float* ffn_w2    = (const float*)d_in[11];
  const float* mediator  = (const float*)d_in[12];
  const float* fuse_w    = (const float*)d_in[13];
  const float* fuse_b    = (const float*)d_in[14];
  const float* o_proj_w  = (const float*)d_in[15];

  const int N = in_sizes[0] / D_;     // 8192
  const int NK = N * K_;
  int capc = (int)ceil((double)NK / E_ * 1.25);
  int C = 1; while (C < capc) C <<= 1; // 4096
  const int NB = (N + 3) / 4;
  const int M3 = N * 3;

  size_t off = 0;
  auto alloc = [&](size_t bytes) -> void* {
    void* r = (char*)d_ws + off;
    off += (bytes + 255) & ~(size_t)255;
    return r;
  };
  float* partials = (float*)alloc(sizeof(float) * (size_t)NB * 17);
  int*   pcounts  = (int*)alloc(sizeof(int) * (size_t)NB * 8);
  int*   counts   = (int*)alloc(sizeof(int) * 8);
  int*   starts   = (int*)alloc(sizeof(int) * 8);
  int*   rows_e   = (int*)alloc(sizeof(int) * 8);
  int*   ctr      = (int*)alloc(sizeof(int) * 8);
  int*   te       = (int*)alloc(sizeof(int) * (size_t)NK);
  int*   keep_nk  = (int*)alloc(sizeof(int) * (size_t)NK);
  int*   rowmap   = (int*)alloc(sizeof(int) * (size_t)NK);
  float* prio     = (float*)alloc(sizeof(float) * (size_t)NK);
  float* tkprob   = (float*)alloc(sizeof(float) * (size_t)NK);

  float* tokens = (float*)alloc(sizeof(float) * (size_t)M3 * D_);
  h16*   tokh   = (h16*)alloc(sizeof(h16) * (size_t)M3 * D_);
  // BIG region: acth (NK*HFF h) / qkvh (M3*2304 h, attn writes in-place into q-slots)
  // then nrmh = sub0, h1h = sub1, fusedh = sub0 (all after qkv is dead).
  h16*   big    = (h16*)alloc(sizeof(h16) * (size_t)M3 * 2304);
  h16*   acth   = big;
  h16*   qkvh   = big;
  h16*   nrmh   = big;                         // sub0: M3*768
  h16*   h1h    = big + (size_t)M3 * D_;       // sub1: M3*768
  h16*   fusedh = big;                         // sub0 reuse at the end

  float* out_fused = (float*)d_out;
  float* out_aux   = out_fused + (size_t)N * D_;
  float* out_topk  = out_aux + 1;

  // ---- router / routing ----
  router_k<<<NB, 256, 0, stream>>>(x, gate_w, partials, pcounts, prio, tkprob, te, out_topk, N);
  stats_k<<<1, 256, 0, stream>>>(partials, pcounts, NB, counts, starts, rows_e, ctr, out_aux, N, C);
  rank_k<<<(NK + 255) / 256, 256, 0, stream>>>(te, prio, counts, starts, ctr, rowmap, keep_nk, NK, C);
  tokinit_k<<<2048, 256, 0, stream>>>(tokens, tokh, mediator, M3 * D_);

  // ---- expert FFN ----
  int ytil = (C + 127) / 128;
  egemm1_k<<<dim3(HFF_ / 64, ytil, E_), 256, 0, stream>>>(x, w13, rowmap, starts, rows_e, acth);
  egemm2_k<<<dim3(D_ / 128, ytil, E_), 256, 0, stream>>>(acth, w2, rowmap, starts, rows_e, x, tokens, tokh);

  // ---- collaborative refinement x2 ----
  for (int step = 0; step < 2; step++) {
    mgemm_k<0><<<dim3(2304 / 128, M3 / 128), 256, 0, stream>>>(tokh, D_, in_proj_w, in_proj_b, nullptr, qkvh, M3, 2304, D_);
    attn_k<<<N, dim3(64, 4), 0, stream>>>(qkvh, keep_nk, N);
    mgemm_k<1><<<dim3(D_ / 128, M3 / 128), 256, 0, stream>>>(qkvh, 2304, out_w, out_b, tokens, nullptr, M3, D_, D_);
    rms1_k<<<M3, 256, 0, stream>>>(tokens, norm1_w);
    rms2_k<<<M3, 256, 0, stream>>>(tokens, norm2_w, nrmh);
    mgemm_k<2><<<dim3(D_ / 128, M3 / 128), 256, 0, stream>>>(nrmh, D_, ffn_w1, nullptr, nullptr, h1h, M3, D_, D_);
    mgemm_k<3><<<dim3(D_ / 128, M3 / 128), 256, 0, stream>>>(h1h, D_, ffn_w2, nullptr, tokens, tokh, M3, D_, D_);
  }

  // ---- fuse + output projection ----
  fuse_k<<<N, 256, 0, stream>>>(tokens, tkprob, keep_nk, fuse_w, fuse_b, fusedh);
  mgemm_k<4><<<dim3(D_ / 128, N / 128), 256, 0, stream>>>(fusedh, D_, o_proj_w, nullptr, out_fused, nullptr, N, D_, D_);
}

// Round 4
// 1842.590 us; speedup vs baseline: 1.5026x; 1.5026x over previous
//
#include <hip/hip_runtime.h>
#include <math.h>
#include <stdint.h>

#define D_ 768
#define E_ 8
#define K_ 2
#define HFF_ 2048

typedef _Float16 h16;
typedef _Float16 h8 __attribute__((ext_vector_type(8)));
typedef float f32x4 __attribute__((ext_vector_type(4)));

__device__ __forceinline__ float wred(float v){
#pragma unroll
  for (int o = 32; o; o >>= 1) v += __shfl_xor(v, o);
  return v;
}
__device__ __forceinline__ int wredi(int v){
#pragma unroll
  for (int o = 32; o; o >>= 1) v += __shfl_xor(v, o);
  return v;
}
__device__ __forceinline__ float gelu_f(float v){
  return 0.5f * v * (1.f + erff(v * 0.70710678118654752f));
}
__device__ __forceinline__ float silu_f(float v){
  return v / (1.f + expf(-v));
}
__device__ __forceinline__ h8 cvt8(float4 u0, float4 u1, float sc){
  h8 t;
  t[0] = (h16)(u0.x * sc); t[1] = (h16)(u0.y * sc);
  t[2] = (h16)(u0.z * sc); t[3] = (h16)(u0.w * sc);
  t[4] = (h16)(u1.x * sc); t[5] = (h16)(u1.y * sc);
  t[6] = (h16)(u1.z * sc); t[7] = (h16)(u1.w * sc);
  return t;
}
// async global->LDS, 16B per lane: HW writes lane i at ldsbase + i*16B.
__device__ __forceinline__ void gload16(const h16* g, h16* l){
  __builtin_amdgcn_global_load_lds((const __attribute__((address_space(1))) void*)g,
                                   (__attribute__((address_space(3))) void*)l,
                                   16, 0, 0);
}

// ---------------- fp32 -> fp16 conversion (optionally scaled) ----------------
__global__ void cvt_k(const float* __restrict__ s, h16* __restrict__ d, int n, float scale)
{
  for (int i = (blockIdx.x * 256 + threadIdx.x) * 4; i < n; i += gridDim.x * 1024) {
    float4 v = *(const float4*)(s + i);
    h16 o0 = (h16)(v.x * scale), o1 = (h16)(v.y * scale);
    h16 o2 = (h16)(v.z * scale), o3 = (h16)(v.w * scale);
    d[i] = o0; d[i + 1] = o1; d[i + 2] = o2; d[i + 3] = o3;
  }
}

// ---------------- router ----------------
__global__ void router_k(const float* __restrict__ x, const float* __restrict__ gw,
                         float* __restrict__ partials, int* __restrict__ pcounts,
                         float* __restrict__ prio, float* __restrict__ tkprob,
                         int* __restrict__ te, float* __restrict__ out_topk, int N)
{
  int wid = threadIdx.x >> 6;
  int lane = threadIdx.x & 63;
  int n = blockIdx.x * 4 + wid;
  __shared__ float lp[4][17];
  __shared__ int lc[4][8];
  float acc[E_];
#pragma unroll
  for (int e = 0; e < E_; e++) acc[e] = 0.f;
  if (n < N) {
    const float* xr = x + (size_t)n * D_;
    for (int c = lane; c < D_; c += 64) {
      float xv = xr[c];
#pragma unroll
      for (int e = 0; e < E_; e++) acc[e] += xv * gw[e * D_ + c];
    }
  }
#pragma unroll
  for (int e = 0; e < E_; e++) acc[e] = wred(acc[e]);
  if (lane == 0) {
    if (n < N) {
      int i0 = 0;
#pragma unroll
      for (int e = 1; e < E_; e++) if (acc[e] > acc[i0]) i0 = e;
      int i1 = -1; float b1 = -3.0e38f;
#pragma unroll
      for (int e = 0; e < E_; e++) if (e != i0 && acc[e] > b1) { b1 = acc[e]; i1 = e; }
      float v0 = acc[i0], v1 = acc[i1];
      float m2 = fmaxf(v0, v1);
      float e0 = expf(v0 - m2), e1 = expf(v1 - m2);
      float p0 = e0 / (e0 + e1), p1 = e1 / (e0 + e1);
      float mx = acc[0];
#pragma unroll
      for (int e = 1; e < E_; e++) mx = fmaxf(mx, acc[e]);
      float se = 0.f;
#pragma unroll
      for (int e = 0; e < E_; e++) se += expf(acc[e] - mx);
      float z = mx + logf(se);
      float inv = 1.f / se;
#pragma unroll
      for (int e = 0; e < E_; e++) lp[wid][e] = expf(acc[e] - mx) * inv;
#pragma unroll
      for (int e = 0; e < E_; e++) lp[wid][8 + e] = (e == i0) ? p0 : ((e == i1) ? p1 : 0.f);
      lp[wid][16] = z * z;
#pragma unroll
      for (int e = 0; e < E_; e++) lc[wid][e] = (e == i0) + (e == i1);
      te[n * 2] = i0; te[n * 2 + 1] = i1;
      prio[n * 2] = v0; prio[n * 2 + 1] = v1;
      tkprob[n * 2] = p0; tkprob[n * 2 + 1] = p1;
      out_topk[n * 2] = (float)i0; out_topk[n * 2 + 1] = (float)i1;
    } else {
      for (int t = 0; t < 17; t++) lp[wid][t] = 0.f;
      for (int e = 0; e < E_; e++) lc[wid][e] = 0;
    }
  }
  __syncthreads();
  int tid = threadIdx.x;
  if (tid < 17)
    partials[(size_t)blockIdx.x * 17 + tid] = lp[0][tid] + lp[1][tid] + lp[2][tid] + lp[3][tid];
  if (tid >= 32 && tid < 40) {
    int e = tid - 32;
    pcounts[(size_t)blockIdx.x * 8 + e] = lc[0][e] + lc[1][e] + lc[2][e] + lc[3][e];
  }
}

// ---------------- stats ----------------
__global__ void stats_k(const float* __restrict__ partials, const int* __restrict__ pcounts,
                        int NB, int* __restrict__ counts, int* __restrict__ starts,
                        int* __restrict__ rows_e, int* __restrict__ ctr,
                        float* __restrict__ aux_out, int N, int C)
{
  __shared__ float ssum[17];
  __shared__ int scnt[8];
  int wave = threadIdx.x >> 6, lane = threadIdx.x & 63;
  for (int v = wave; v < 17; v += 4) {
    float s = 0.f;
    for (int b = lane; b < NB; b += 64) s += partials[(size_t)b * 17 + v];
    s = wred(s);
    if (lane == 0) ssum[v] = s;
  }
  for (int e = wave; e < 8; e += 4) {
    int c = 0;
    for (int b = lane; b < NB; b += 64) c += pcounts[(size_t)b * 8 + e];
    c = wredi(c);
    if (lane == 0) scnt[e] = c;
  }
  __syncthreads();
  if (threadIdx.x == 0) {
    int st = 0, kept = 0;
    float bal = 0.f;
    for (int e = 0; e < E_; e++) {
      counts[e] = scnt[e]; starts[e] = st; st += scnt[e];
      int r = scnt[e] < C ? scnt[e] : C;
      rows_e[e] = r; kept += r;
      bal += (ssum[e] / N) * (ssum[8 + e] / N);
      ctr[e] = 0;
    }
    int NK = N * K_;
    float aux = 0.01f * bal * (float)E_ + 0.001f * (ssum[16] / N)
              + 0.001f * (1.f - (float)kept / (float)NK);
    aux_out[0] = aux;
  }
}

// ---------------- rank/slot assignment ----------------
__global__ void rank_k(const int* __restrict__ te, const float* __restrict__ prio,
                       const int* __restrict__ counts, const int* __restrict__ starts,
                       int* __restrict__ ctr, int* __restrict__ rowmap,
                       int* __restrict__ keep_nk, int NK, int C)
{
  int i = blockIdx.x * 256 + threadIdx.x;
  if (i >= NK) return;
  int e = te[i];
  int cnt = counts[e];
  int pos;
  if (cnt <= C) {
    pos = atomicAdd(&ctr[e], 1);
  } else {
    float p = prio[i]; int r = 0;
    for (int j = 0; j < NK; j++) {
      if (te[j] == e) { float pj = prio[j]; r += (pj > p) || (pj == p && j < i); }
    }
    pos = r;
  }
  int kp = pos < C ? 1 : 0;
  keep_nk[i] = kp;
  if (kp) rowmap[starts[e] + pos] = i;
}

// ---------------- tokens init ----------------
__global__ void tokinit_k(float* __restrict__ tokens, h16* __restrict__ tokh,
                          const float* __restrict__ med, int total)
{
  for (int idx = blockIdx.x * 256 + threadIdx.x; idx < total; idx += gridDim.x * 256) {
    int r = idx % (3 * D_);
    float v = (r >= 2 * D_) ? med[r - 2 * D_] : 0.f;
    tokens[idx] = v; tokh[idx] = (h16)v;
  }
}

// =====================================================================================
// MFMA GEMM core: C(M,N)=A(M,K)@B(N,K)^T. A fp16 via global_load_lds (m97 pattern).
// B: fp16 via global_load_lds if BH, else fp32 reg-stage+cvt (fallback).
// 128x128 tile, BK=64, 4 waves, fragment-ordered LDS: unit u at u*1024B, lane l +l*16B.
// EPI: 0 +bias->C16 (qkv) ; 1 C32+=acc+bias (resid) ; 2 gelu->C16 ; 3 t=acc+C32 ->C32&C16 ; 4 ->C32
// =====================================================================================
template<int EPI, bool BH>
__global__ __launch_bounds__(256, 2) void mgemm_k(
    const h16* __restrict__ A, int lda, const void* __restrict__ Bv,
    const float* __restrict__ bias, float* C32, h16* C16, int M, int N, int K)
{
  __shared__ __align__(16) h16 ls[16384];
  const int tid = threadIdx.x;
  const int lane = tid & 63, wave = tid >> 6;
  const int wm = wave >> 1, wn = wave & 1;
  const int lr = lane & 15, lk = lane >> 4;
  const int m0 = blockIdx.y * 128, n0 = blockIdx.x * 128;

  f32x4 acc[4][4];
#pragma unroll
  for (int i = 0; i < 4; ++i)
#pragma unroll
    for (int j = 0; j < 4; ++j) acc[i][j] = f32x4{0.f, 0.f, 0.f, 0.f};

  const int ldsbase = (wave < 2) ? wave * 4096 : 8192 + (wave - 2) * 4096;
  const int koff = (wave & 1) * 32 + lk * 8;
  const h16* Bh = (const h16*)Bv;
  const float* Bf = (const float*)Bv;
  size_t srow[8];
  if (wave < 2) {
#pragma unroll
    for (int j = 0; j < 8; ++j) srow[j] = (size_t)(m0 + j * 16 + lr) * (size_t)lda;
  } else {
#pragma unroll
    for (int j = 0; j < 8; ++j) srow[j] = (size_t)(n0 + j * 16 + lr) * (size_t)K;
  }

  const int nkt = K >> 6;
  for (int kt = 0; kt < nkt; ++kt) {
    const int kb = kt * 64 + koff;
    __syncthreads();
    if (wave < 2) {
#pragma unroll
      for (int j = 0; j < 8; ++j) gload16(A + srow[j] + kb, &ls[ldsbase + j * 512]);
    } else if (BH) {
#pragma unroll
      for (int j = 0; j < 8; ++j) gload16(Bh + srow[j] + kb, &ls[ldsbase + j * 512]);
    } else {
#pragma unroll
      for (int j = 0; j < 8; ++j) {
        float4 u0 = *(const float4*)(Bf + srow[j] + kb);
        float4 u1 = *(const float4*)(Bf + srow[j] + kb + 4);
        *(h8*)&ls[ldsbase + j * 512 + lane * 8] = cvt8(u0, u1, 1.f);
      }
    }
    __syncthreads();
#pragma unroll
    for (int kc = 0; kc < 2; ++kc) {
      h8 af[4], bf[4];
#pragma unroll
      for (int i = 0; i < 4; ++i) af[i] = *(const h8*)&ls[(kc * 8 + wm * 4 + i) * 512 + lane * 8];
#pragma unroll
      for (int j = 0; j < 4; ++j) bf[j] = *(const h8*)&ls[8192 + (kc * 8 + wn * 4 + j) * 512 + lane * 8];
#pragma unroll
      for (int i = 0; i < 4; ++i)
#pragma unroll
        for (int j = 0; j < 4; ++j)
          acc[i][j] = __builtin_amdgcn_mfma_f32_16x16x32_f16(af[i], bf[j], acc[i][j], 0, 0, 0);
    }
  }

#pragma unroll
  for (int i = 0; i < 4; ++i) {
    const int row0 = m0 + (wm * 4 + i) * 16 + lk * 4;
#pragma unroll
    for (int j = 0; j < 4; ++j) {
      const int col = n0 + (wn * 4 + j) * 16 + lr;
      const float bv = (EPI == 0 || EPI == 1) ? bias[col] : 0.f;
#pragma unroll
      for (int r = 0; r < 4; ++r) {
        const size_t o = (size_t)(row0 + r) * N + col;
        const float v = acc[i][j][r];
        if (EPI == 0)      { C16[o] = (h16)(v + bv); }
        else if (EPI == 1) { C32[o] += v + bv; }
        else if (EPI == 2) { C16[o] = (h16)gelu_f(v); }
        else if (EPI == 3) { float t = v + C32[o]; C32[o] = t; C16[o] = (h16)t; }
        else               { C32[o] = v; }
      }
    }
  }
}

// ---------------- expert GEMM1: act = silu(2x Wg^T)*(2x Wu^T), gathered rows ----------------
// B units j: cg=j>>1 (out colgroup), half=j&1 (0 gate / 1 up). w13h pre-scaled by 2.
template<bool BH>
__global__ __launch_bounds__(256, 2) void egemm1_k(
    const float* __restrict__ x, const h16* __restrict__ xh,
    const float* __restrict__ w13, const h16* __restrict__ w13h,
    const int* __restrict__ rowmap, const int* __restrict__ starts,
    const int* __restrict__ rows_e, h16* __restrict__ acth)
{
  const int e = blockIdx.z;
  const int rows = rows_e[e], st = starts[e];
  const int r0 = blockIdx.y * 128;
  if (r0 >= rows) return;
  const int h0 = blockIdx.x * 64;

  __shared__ __align__(16) h16 ls[16384];
  const int tid = threadIdx.x;
  const int lane = tid & 63, wave = tid >> 6;
  const int wm = wave >> 1, wn = wave & 1;
  const int lr = lane & 15, lk = lane >> 4;

  f32x4 acc[4][4];
#pragma unroll
  for (int i = 0; i < 4; ++i)
#pragma unroll
    for (int j = 0; j < 4; ++j) acc[i][j] = f32x4{0.f, 0.f, 0.f, 0.f};

  const int ldsbase = (wave < 2) ? wave * 4096 : 8192 + (wave - 2) * 4096;
  const int koff = (wave & 1) * 32 + lk * 8;
  size_t srow[8];
  if (wave < 2) {
#pragma unroll
    for (int j = 0; j < 8; ++j) {
      int r = r0 + j * 16 + lr; if (r >= rows) r = rows - 1;
      srow[j] = (size_t)(rowmap[st + r] >> 1) * D_;
    }
  } else {
#pragma unroll
    for (int j = 0; j < 8; ++j)
      srow[j] = ((size_t)e * 4096 + (size_t)(j & 1) * 2048 + h0 + (j >> 1) * 16 + lr) * D_;
  }

  for (int kt = 0; kt < D_ / 64; ++kt) {
    const int kb = kt * 64 + koff;
    __syncthreads();
    if (BH) {
      const h16* src = (wave < 2) ? xh : w13h;
#pragma unroll
      for (int j = 0; j < 8; ++j) gload16(src + srow[j] + kb, &ls[ldsbase + j * 512]);
    } else {
      const float* src = (wave < 2) ? x : w13;
      const float sc = (wave < 2) ? 2.f : 1.f;
#pragma unroll
      for (int j = 0; j < 8; ++j) {
        float4 u0 = *(const float4*)(src + srow[j] + kb);
        float4 u1 = *(const float4*)(src + srow[j] + kb + 4);
        *(h8*)&ls[ldsbase + j * 512 + lane * 8] = cvt8(u0, u1, sc);
      }
    }
    __syncthreads();
#pragma unroll
    for (int kc = 0; kc < 2; ++kc) {
      h8 af[4], bf[4];
#pragma unroll
      for (int i = 0; i < 4; ++i) af[i] = *(const h8*)&ls[(kc * 8 + wm * 4 + i) * 512 + lane * 8];
#pragma unroll
      for (int j = 0; j < 4; ++j) bf[j] = *(const h8*)&ls[8192 + (kc * 8 + wn * 4 + j) * 512 + lane * 8];
#pragma unroll
      for (int i = 0; i < 4; ++i)
#pragma unroll
        for (int j = 0; j < 4; ++j)
          acc[i][j] = __builtin_amdgcn_mfma_f32_16x16x32_f16(af[i], bf[j], acc[i][j], 0, 0, 0);
    }
  }

#pragma unroll
  for (int i = 0; i < 4; ++i) {
    const int rloc = r0 + (wm * 4 + i) * 16 + lk * 4;
#pragma unroll
    for (int jc = 0; jc < 2; ++jc) {
      const int col = h0 + (wn * 2 + jc) * 16 + lr;
#pragma unroll
      for (int r = 0; r < 4; ++r) {
        const int rr = rloc + r;
        if (rr < rows) {
          float g = acc[i][2 * jc][r], u = acc[i][2 * jc + 1][r];
          acth[(size_t)(st + rr) * HFF_ + col] = (h16)(silu_f(g) * u);
        }
      }
    }
  }
}

// ---------------- expert GEMM2: tokens[t,l] = x[t] + act @ w2^T (scatter) ----------------
template<bool BH>
__global__ __launch_bounds__(256, 2) void egemm2_k(
    const h16* __restrict__ acth, const float* __restrict__ w2, const h16* __restrict__ w2h,
    const int* __restrict__ rowmap, const int* __restrict__ starts,
    const int* __restrict__ rows_e, const float* __restrict__ x,
    float* __restrict__ tokens, h16* __restrict__ tokh)
{
  const int e = blockIdx.z;
  const int rows = rows_e[e], st = starts[e];
  const int r0 = blockIdx.y * 128;
  if (r0 >= rows) return;
  const int n0 = blockIdx.x * 128;

  __shared__ __align__(16) h16 ls[16384];
  const int tid = threadIdx.x;
  const int lane = tid & 63, wave = tid >> 6;
  const int wm = wave >> 1, wn = wave & 1;
  const int lr = lane & 15, lk = lane >> 4;

  f32x4 acc[4][4];
#pragma unroll
  for (int i = 0; i < 4; ++i)
#pragma unroll
    for (int j = 0; j < 4; ++j) acc[i][j] = f32x4{0.f, 0.f, 0.f, 0.f};

  const int ldsbase = (wave < 2) ? wave * 4096 : 8192 + (wave - 2) * 4096;
  const int koff = (wave & 1) * 32 + lk * 8;
  size_t srow[8];
  if (wave < 2) {
#pragma unroll
    for (int j = 0; j < 8; ++j) {
      int r = r0 + j * 16 + lr; if (r >= rows) r = rows - 1;
      srow[j] = (size_t)(st + r) * HFF_;
    }
  } else {
#pragma unroll
    for (int j = 0; j < 8; ++j)
      srow[j] = ((size_t)e * D_ + n0 + j * 16 + lr) * HFF_;
  }

  for (int kt = 0; kt < HFF_ / 64; ++kt) {
    const int kb = kt * 64 + koff;
    __syncthreads();
    if (wave < 2) {
#pragma unroll
      for (int j = 0; j < 8; ++j) gload16(acth + srow[j] + kb, &ls[ldsbase + j * 512]);
    } else if (BH) {
#pragma unroll
      for (int j = 0; j < 8; ++j) gload16(w2h + srow[j] + kb, &ls[ldsbase + j * 512]);
    } else {
#pragma unroll
      for (int j = 0; j < 8; ++j) {
        float4 u0 = *(const float4*)(w2 + srow[j] + kb);
        float4 u1 = *(const float4*)(w2 + srow[j] + kb + 4);
        *(h8*)&ls[ldsbase + j * 512 + lane * 8] = cvt8(u0, u1, 1.f);
      }
    }
    __syncthreads();
#pragma unroll
    for (int kc = 0; kc < 2; ++kc) {
      h8 af[4], bf[4];
#pragma unroll
      for (int i = 0; i < 4; ++i) af[i] = *(const h8*)&ls[(kc * 8 + wm * 4 + i) * 512 + lane * 8];
#pragma unroll
      for (int j = 0; j < 4; ++j) bf[j] = *(const h8*)&ls[8192 + (kc * 8 + wn * 4 + j) * 512 + lane * 8];
#pragma unroll
      for (int i = 0; i < 4; ++i)
#pragma unroll
        for (int j = 0; j < 4; ++j)
          acc[i][j] = __builtin_amdgcn_mfma_f32_16x16x32_f16(af[i], bf[j], acc[i][j], 0, 0, 0);
    }
  }

#pragma unroll
  for (int i = 0; i < 4; ++i) {
    const int rloc = r0 + (wm * 4 + i) * 16 + lk * 4;
#pragma unroll
    for (int j = 0; j < 4; ++j) {
      const int col = n0 + (wn * 4 + j) * 16 + lr;
#pragma unroll
      for (int r = 0; r < 4; ++r) {
        const int rr = rloc + r;
        if (rr < rows) {
          int item = rowmap[st + rr];
          int t = item >> 1, l = item & 1;
          size_t o = ((size_t)t * 3 + l) * D_ + col;
          float v = acc[i][j][r] + x[(size_t)t * D_ + col];
          tokens[o] = v; tokh[o] = (h16)v;
        }
      }
    }
  }
}

// ---------------- attention over L=3 tokens, IN-PLACE into q-slots of qkv ----------------
__global__ void attn_k(h16* qkv, const int* __restrict__ keep_nk, int N)
{
  int n = blockIdx.x;
  int h = threadIdx.y, lane = threadIdx.x;
  h16* base = qkv + (size_t)n * 3 * 2304;
  float qr[3][3], kr[3][3], vr[3][3];
#pragma unroll
  for (int l2 = 0; l2 < 3; l2++) {
    const h16* row = base + l2 * 2304 + h * 192;
#pragma unroll
    for (int c = 0; c < 3; c++) {
      qr[l2][c] = (float)row[c * 64 + lane];
      kr[l2][c] = (float)row[768 + c * 64 + lane];
      vr[l2][c] = (float)row[1536 + c * 64 + lane];
    }
  }
  const float scale = 0.07216878364870323f; // 1/sqrt(192)
  float bj0 = keep_nk[n * 2] ? 0.f : -1e9f;
  float bj1 = keep_nk[n * 2 + 1] ? 0.f : -1e9f;
  float a[3][3];
#pragma unroll
  for (int i2 = 0; i2 < 3; i2++) {
    float s0 = wred(qr[i2][0] * kr[0][0] + qr[i2][1] * kr[0][1] + qr[i2][2] * kr[0][2]) * scale + bj0;
    float s1 = wred(qr[i2][0] * kr[1][0] + qr[i2][1] * kr[1][1] + qr[i2][2] * kr[1][2]) * scale + bj1;
    float s2 = wred(qr[i2][0] * kr[2][0] + qr[i2][1] * kr[2][1] + qr[i2][2] * kr[2][2]) * scale;
    float m = fmaxf(s0, fmaxf(s1, s2));
    float e0 = expf(s0 - m), e1 = expf(s1 - m), e2 = expf(s2 - m);
    float inv = 1.f / (e0 + e1 + e2);
    a[i2][0] = e0 * inv; a[i2][1] = e1 * inv; a[i2][2] = e2 * inv;
  }
#pragma unroll
  for (int i2 = 0; i2 < 3; i2++) {
    h16* dst = base + i2 * 2304 + h * 192;
#pragma unroll
    for (int c = 0; c < 3; c++)
      dst[c * 64 + lane] = (h16)(a[i2][0] * vr[0][c] + a[i2][1] * vr[1][c] + a[i2][2] * vr[2][c]);
  }
}

// ---------------- fused RMSNorm: tokens = rms(tokens)*w1 ; nrmh = fp16(rms(tokens')*w2) ------
__global__ void rms12_k(float* tokens, const float* __restrict__ w1,
                        const float* __restrict__ w2, h16* __restrict__ nrmh)
{
  int row = blockIdx.x, tid = threadIdx.x;
  float* s = tokens + (size_t)row * D_;
  float v0 = s[tid], v1 = s[tid + 256], v2 = s[tid + 512];
  __shared__ float redA[4], redB[4];
  float ss = v0 * v0 + v1 * v1 + v2 * v2;
  float wsum = wred(ss);
  if ((tid & 63) == 0) redA[tid >> 6] = wsum;
  __syncthreads();
  float tot = redA[0] + redA[1] + redA[2] + redA[3];
  float r = 1.f / sqrtf(tot * (1.f / 768.f) + 1e-6f);
  float t0 = v0 * r * w1[tid];
  float t1 = v1 * r * w1[tid + 256];
  float t2 = v2 * r * w1[tid + 512];
  float ss2 = t0 * t0 + t1 * t1 + t2 * t2;
  float wsum2 = wred(ss2);
  if ((tid & 63) == 0) redB[tid >> 6] = wsum2;
  __syncthreads();
  float tot2 = redB[0] + redB[1] + redB[2] + redB[3];
  float r2 = 1.f / sqrtf(tot2 * (1.f / 768.f) + 1e-6f);
  s[tid] = t0; s[tid + 256] = t1; s[tid + 512] = t2;
  h16* dd = nrmh + (size_t)row * D_;
  dd[tid]       = (h16)(t0 * r2 * w2[tid]);
  dd[tid + 256] = (h16)(t1 * r2 * w2[tid + 256]);
  dd[tid + 512] = (h16)(t2 * r2 * w2[tid + 512]);
}

// ---------------- final fuse ----------------
__global__ void fuse_k(const float* __restrict__ tokens, const float* __restrict__ tkprob,
                       const int* __restrict__ keep_nk, const float* __restrict__ fw,
                       const float* __restrict__ fb, h16* __restrict__ out)
{
  int n = blockIdx.x; int tid = threadIdx.x;
  const float* t0 = tokens + ((size_t)n * 3 + 0) * D_;
  const float* t1 = tokens + ((size_t)n * 3 + 1) * D_;
  const float* md = tokens + ((size_t)n * 3 + 2) * D_;
  float p = md[tid] * fw[tid] + md[tid + 256] * fw[tid + 256] + md[tid + 512] * fw[tid + 512];
  __shared__ float red[4];
  float wsum = wred(p);
  if ((tid & 63) == 0) red[tid >> 6] = wsum;
  __syncthreads();
  float dot = red[0] + red[1] + red[2] + red[3];
  float g = 1.f / (1.f + expf(-(dot + fb[0])));
  float tp0 = keep_nk[n * 2] ? tkprob[n * 2] : 0.f;
  float tp1 = keep_nk[n * 2 + 1] ? tkprob[n * 2 + 1] : 0.f;
  float den = tp0 + tp1;
  float w0 = den > 0.f ? tp0 / den : 0.f;
  float w1 = den > 0.f ? tp1 / den : 0.f;
  h16* d = out + (size_t)n * D_;
#pragma unroll
  for (int c3 = 0; c3 < 3; c3++) {
    int c = tid + c3 * 256;
    d[c] = (h16)(g * md[c] + (1.f - g) * (w0 * t0[c] + w1 * t1[c]));
  }
}

template<bool BH>
static void run_pipeline(const float* x, const float* gate_w, const float* w13,
                         const float* w2, const float* in_proj_w, const float* in_proj_b,
                         const float* out_w, const float* out_b, const float* norm1_w,
                         const float* norm2_w, const float* ffn_w1, const float* ffn_w2,
                         const float* mediator, const float* fuse_w, const float* fuse_b,
                         const float* o_proj_w,
                         // ws views
                         float* partials, int* pcounts, int* counts, int* starts,
                         int* rows_e, int* ctr, int* te, int* keep_nk, int* rowmap,
                         float* prio, float* tkprob, float* tokens, h16* tokh, h16* big,
                         h16* xh, h16* w13h, h16* w2h, h16* inprojh, h16* outwh,
                         h16* ffn1h, h16* ffn2h, h16* oprojh,
                         float* out_fused, float* out_aux, float* out_topk,
                         int N, int C, int NB, int M3, hipStream_t stream)
{
  h16* acth   = big;
  h16* qkvh   = big;
  h16* nrmh   = big;                       // sub0 after qkv dead
  h16* h1h    = big + (size_t)M3 * D_;     // sub1
  h16* fusedh = big;

  if (BH) {
    cvt_k<<<512,  256, 0, stream>>>(x, xh, N * D_, 1.0f);
    cvt_k<<<2048, 256, 0, stream>>>(w13, w13h, E_ * 2 * HFF_ * D_, 2.0f);
    cvt_k<<<2048, 256, 0, stream>>>(w2, w2h, E_ * D_ * HFF_, 1.0f);
    cvt_k<<<256,  256, 0, stream>>>(in_proj_w, inprojh, 3 * D_ * D_, 1.0f);
    cvt_k<<<128,  256, 0, stream>>>(out_w, outwh, D_ * D_, 1.0f);
    cvt_k<<<128,  256, 0, stream>>>(ffn_w1, ffn1h, D_ * D_, 1.0f);
    cvt_k<<<128,  256, 0, stream>>>(ffn_w2, ffn2h, D_ * D_, 1.0f);
    cvt_k<<<128,  256, 0, stream>>>(o_proj_w, oprojh, D_ * D_, 1.0f);
  }

  router_k<<<NB, 256, 0, stream>>>(x, gate_w, partials, pcounts, prio, tkprob, te, out_topk, N);
  stats_k<<<1, 256, 0, stream>>>(partials, pcounts, NB, counts, starts, rows_e, ctr, out_aux, N, C);
  rank_k<<<(N * K_ + 255) / 256, 256, 0, stream>>>(te, prio, counts, starts, ctr, rowmap, keep_nk, N * K_, C);
  tokinit_k<<<2048, 256, 0, stream>>>(tokens, tokh, mediator, M3 * D_);

  int ytil = (C + 127) / 128;
  egemm1_k<BH><<<dim3(HFF_ / 64, ytil, E_), 256, 0, stream>>>(x, xh, w13, w13h, rowmap, starts, rows_e, acth);
  egemm2_k<BH><<<dim3(D_ / 128, ytil, E_), 256, 0, stream>>>(acth, w2, w2h, rowmap, starts, rows_e, x, tokens, tokh);

  const void* inpB  = BH ? (const void*)inprojh : (const void*)in_proj_w;
  const void* outB  = BH ? (const void*)outwh   : (const void*)out_w;
  const void* f1B   = BH ? (const void*)ffn1h   : (const void*)ffn_w1;
  const void* f2B   = BH ? (const void*)ffn2h   : (const void*)ffn_w2;
  const void* opB   = BH ? (const void*)oprojh  : (const void*)o_proj_w;

  for (int step = 0; step < 2; step++) {
    mgemm_k<0, BH><<<dim3(2304 / 128, M3 / 128), 256, 0, stream>>>(tokh, D_, inpB, in_proj_b, nullptr, qkvh, M3, 2304, D_);
    attn_k<<<N, dim3(64, 4), 0, stream>>>(qkvh, keep_nk, N);
    mgemm_k<1, BH><<<dim3(D_ / 128, M3 / 128), 256, 0, stream>>>(qkvh, 2304, outB, out_b, tokens, nullptr, M3, D_, D_);
    rms12_k<<<M3, 256, 0, stream>>>(tokens, norm1_w, norm2_w, nrmh);
    mgemm_k<2, BH><<<dim3(D_ / 128, M3 / 128), 256, 0, stream>>>(nrmh, D_, f1B, nullptr, nullptr, h1h, M3, D_, D_);
    mgemm_k<3, BH><<<dim3(D_ / 128, M3 / 128), 256, 0, stream>>>(h1h, D_, f2B, nullptr, tokens, tokh, M3, D_, D_);
  }

  fuse_k<<<N, 256, 0, stream>>>(tokens, tkprob, keep_nk, fuse_w, fuse_b, fusedh);
  mgemm_k<4, BH><<<dim3(D_ / 128, N / 128), 256, 0, stream>>>(fusedh, D_, opB, nullptr, out_fused, nullptr, N, D_, D_);
}

extern "C" void kernel_launch(void* const* d_in, const int* in_sizes, int n_in,
                              void* d_out, int out_size, void* d_ws, size_t ws_size,
                              hipStream_t stream) {
  const float* x         = (const float*)d_in[0];
  const float* gate_w    = (const float*)d_in[1];
  const float* w13       = (const float*)d_in[2];
  const float* w2        = (const float*)d_in[3];
  const float* in_proj_w = (const float*)d_in[4];
  const float* in_proj_b = (const float*)d_in[5];
  const float* out_w     = (const float*)d_in[6];
  const float* out_b     = (const float*)d_in[7];
  const float* norm1_w   = (const float*)d_in[8];
  const float* norm2_w   = (const float*)d_in[9];
  const float* ffn_w1    = (const float*)d_in[10];
  const float* ffn_w2    = (const float*)d_in[11];
  const float* mediator  = (const float*)d_in[12];
  const float* fuse_w    = (const float*)d_in[13];
  const float* fuse_b    = (const float*)d_in[14];
  const float* o_proj_w  = (const float*)d_in[15];

  const int N = in_sizes[0] / D_;     // 8192
  const int NK = N * K_;
  int capc = (int)ceil((double)NK / E_ * 1.25);
  int C = 1; while (C < capc) C <<= 1; // 4096
  const int NB = (N + 3) / 4;
  const int M3 = N * 3;

  size_t off = 0;
  auto alloc = [&](size_t bytes) -> void* {
    void* r = (char*)d_ws + off;
    off += (bytes + 255) & ~(size_t)255;
    return r;
  };
  // ---- base region (always fits; round-3 layout) ----
  float* partials = (float*)alloc(sizeof(float) * (size_t)NB * 17);
  int*   pcounts  = (int*)alloc(sizeof(int) * (size_t)NB * 8);
  int*   counts   = (int*)alloc(sizeof(int) * 8);
  int*   starts   = (int*)alloc(sizeof(int) * 8);
  int*   rows_e   = (int*)alloc(sizeof(int) * 8);
  int*   ctr      = (int*)alloc(sizeof(int) * 8);
  int*   te       = (int*)alloc(sizeof(int) * (size_t)NK);
  int*   keep_nk  = (int*)alloc(sizeof(int) * (size_t)NK);
  int*   rowmap   = (int*)alloc(sizeof(int) * (size_t)NK);
  float* prio     = (float*)alloc(sizeof(float) * (size_t)NK);
  float* tkprob   = (float*)alloc(sizeof(float) * (size_t)NK);
  float* tokens   = (float*)alloc(sizeof(float) * (size_t)M3 * D_);
  h16*   tokh     = (h16*)alloc(sizeof(h16) * (size_t)M3 * D_);
  h16*   big      = (h16*)alloc(sizeof(h16) * (size_t)M3 * 2304);
  // ---- optional fp16-weight region ----
  h16* xh      = (h16*)alloc(sizeof(h16) * (size_t)N * D_);
  h16* w13h    = (h16*)alloc(sizeof(h16) * (size_t)E_ * 2 * HFF_ * D_);
  h16* w2h     = (h16*)alloc(sizeof(h16) * (size_t)E_ * D_ * HFF_);
  h16* inprojh = (h16*)alloc(sizeof(h16) * (size_t)3 * D_ * D_);
  h16* outwh   = (h16*)alloc(sizeof(h16) * (size_t)D_ * D_);
  h16* ffn1h   = (h16*)alloc(sizeof(h16) * (size_t)D_ * D_);
  h16* ffn2h   = (h16*)alloc(sizeof(h16) * (size_t)D_ * D_);
  h16* oprojh  = (h16*)alloc(sizeof(h16) * (size_t)D_ * D_);
  const bool use_bh = (off <= ws_size);

  float* out_fused = (float*)d_out;
  float* out_aux   = out_fused + (size_t)N * D_;
  float* out_topk  = out_aux + 1;

  if (use_bh)
    run_pipeline<true>(x, gate_w, w13, w2, in_proj_w, in_proj_b, out_w, out_b, norm1_w,
                       norm2_w, ffn_w1, ffn_w2, mediator, fuse_w, fuse_b, o_proj_w,
                       partials, pcounts, counts, starts, rows_e, ctr, te, keep_nk, rowmap,
                       prio, tkprob, tokens, tokh, big, xh, w13h, w2h, inprojh, outwh,
                       ffn1h, ffn2h, oprojh, out_fused, out_aux, out_topk,
                       N, C, NB, M3, stream);
  else
    run_pipeline<false>(x, gate_w, w13, w2, in_proj_w, in_proj_b, out_w, out_b, norm1_w,
                        norm2_w, ffn_w1, ffn_w2, mediator, fuse_w, fuse_b, o_proj_w,
                        partials, pcounts, counts, starts, rows_e, ctr, te, keep_nk, rowmap,
                        prio, tkprob, tokens, tokh, big, xh, w13h, w2h, inprojh, outwh,
                        ffn1h, ffn2h, oprojh, out_fused, out_aux, out_topk,
                        N, C, NB, M3, stream);
}

// Round 6
// 1786.348 us; speedup vs baseline: 1.5499x; 1.0315x over previous
//
#include <hip/hip_runtime.h>
#include <math.h>
#include <stdint.h>

#define D_ 768
#define E_ 8
#define K_ 2
#define HFF_ 2048

typedef _Float16 h16;
typedef _Float16 h8 __attribute__((ext_vector_type(8)));
typedef float f32x4 __attribute__((ext_vector_type(4)));

__device__ __forceinline__ float wred(float v){
#pragma unroll
  for (int o = 32; o; o >>= 1) v += __shfl_xor(v, o);
  return v;
}
__device__ __forceinline__ int wredi(int v){
#pragma unroll
  for (int o = 32; o; o >>= 1) v += __shfl_xor(v, o);
  return v;
}
__device__ __forceinline__ float gelu_f(float v){
  return 0.5f * v * (1.f + erff(v * 0.70710678118654752f));
}
__device__ __forceinline__ float silu_f(float v){
  return v / (1.f + expf(-v));
}
__device__ __forceinline__ h8 cvt8(float4 u0, float4 u1, float sc){
  h8 t;
  t[0] = (h16)(u0.x * sc); t[1] = (h16)(u0.y * sc);
  t[2] = (h16)(u0.z * sc); t[3] = (h16)(u0.w * sc);
  t[4] = (h16)(u1.x * sc); t[5] = (h16)(u1.y * sc);
  t[6] = (h16)(u1.z * sc); t[7] = (h16)(u1.w * sc);
  return t;
}
// async global->LDS, 16B per lane: HW writes lane i at ldsbase + i*16B.
__device__ __forceinline__ void gload16(const h16* g, h16* l){
  __builtin_amdgcn_global_load_lds((const __attribute__((address_space(1))) void*)g,
                                   (__attribute__((address_space(3))) void*)l,
                                   16, 0, 0);
}

// =====================================================================================
// Pipelined MFMA core (BK=32, double-buffered LDS, counted vmcnt, raw barriers).
// Each wave stages 4 units (16 rows x 32 k each) of its side (waves 0-1: A, 2-3: B)
// per K-step; next K-step's 4 DMA loads stay in flight across the barriers (vmcnt(4)).
// LDS: buffer sel at sel*8192 halves; A units u*512, B at 4096+u*512.
// Safety invariants (audited r5): barrier counts uniform across waves; only the 4
// staging DMAs are in the vmcnt window (sched_barrier fences); each staging wave
// drains its own tile-k loads before the barrier, so consumers see landed data;
// tile k+2's writes hit the buffer read at k only after the end-of-k barrier.
// =====================================================================================
__device__ __forceinline__ void mfma_core(const h16* __restrict__ src,
    const size_t* srow, int nkt, h16* ls, f32x4 (&acc)[4][4], int lane, int wave)
{
  const int wm = wave >> 1, wn = wave & 1;
  const int lk8 = (lane >> 4) * 8;
  const int ub0 = ((wave >= 2) ? 4096 : 0) + (wave & 1) * 2048;

  { // prologue: stage tile 0 into buffer 0
    const h16* s0 = src + lk8;
#pragma unroll
    for (int j = 0; j < 4; ++j)
      gload16(s0 + srow[j], &ls[ub0 + j * 512]);
  }
  for (int kt = 0; kt < nkt; ++kt) {
    const int sel = kt & 1;
    if (kt + 1 < nkt) {
      const h16* s0 = src + (kt + 1) * 32 + lk8;
      const int db = (sel ^ 1) * 8192 + ub0;
#pragma unroll
      for (int j = 0; j < 4; ++j)
        gload16(s0 + srow[j], &ls[db + j * 512]);
      __builtin_amdgcn_sched_barrier(0);
      asm volatile("s_waitcnt vmcnt(4)" ::: "memory");   // cur tile done, next 4 in flight
    } else {
      __builtin_amdgcn_sched_barrier(0);
      asm volatile("s_waitcnt vmcnt(0)" ::: "memory");   // tail drain
    }
    __builtin_amdgcn_sched_barrier(0);
    __builtin_amdgcn_s_barrier();
    __builtin_amdgcn_sched_barrier(0);
    const int ab = sel * 8192 + wm * 2048 + lane * 8;
    const int bb = sel * 8192 + 4096 + wn * 2048 + lane * 8;
    h8 af[4], bf[4];
#pragma unroll
    for (int i = 0; i < 4; ++i) af[i] = *(const h8*)&ls[ab + i * 512];
#pragma unroll
    for (int j = 0; j < 4; ++j) bf[j] = *(const h8*)&ls[bb + j * 512];
#pragma unroll
    for (int i = 0; i < 4; ++i)
#pragma unroll
      for (int j = 0; j < 4; ++j)
        acc[i][j] = __builtin_amdgcn_mfma_f32_16x16x32_f16(af[i], bf[j], acc[i][j], 0, 0, 0);
    __builtin_amdgcn_sched_barrier(0);
    __builtin_amdgcn_s_barrier();
    __builtin_amdgcn_sched_barrier(0);
  }
}

// ---------------- fp32 -> fp16 conversion (optionally scaled) ----------------
__global__ void cvt_k(const float* __restrict__ s, h16* __restrict__ d, int n, float scale)
{
  for (int i = (blockIdx.x * 256 + threadIdx.x) * 4; i < n; i += gridDim.x * 1024) {
    float4 v = *(const float4*)(s + i);
    h16 o0 = (h16)(v.x * scale), o1 = (h16)(v.y * scale);
    h16 o2 = (h16)(v.z * scale), o3 = (h16)(v.w * scale);
    d[i] = o0; d[i + 1] = o1; d[i + 2] = o2; d[i + 3] = o3;
  }
}

// ---------------- router ----------------
__global__ void router_k(const float* __restrict__ x, const float* __restrict__ gw,
                         float* __restrict__ partials, int* __restrict__ pcounts,
                         float* __restrict__ prio, float* __restrict__ tkprob,
                         int* __restrict__ te, float* __restrict__ out_topk, int N)
{
  int wid = threadIdx.x >> 6;
  int lane = threadIdx.x & 63;
  int n = blockIdx.x * 4 + wid;
  __shared__ float lp[4][17];
  __shared__ int lc[4][8];
  float acc[E_];
#pragma unroll
  for (int e = 0; e < E_; e++) acc[e] = 0.f;
  if (n < N) {
    const float* xr = x + (size_t)n * D_;
    for (int c = lane; c < D_; c += 64) {
      float xv = xr[c];
#pragma unroll
      for (int e = 0; e < E_; e++) acc[e] += xv * gw[e * D_ + c];
    }
  }
#pragma unroll
  for (int e = 0; e < E_; e++) acc[e] = wred(acc[e]);
  if (lane == 0) {
    if (n < N) {
      int i0 = 0;
#pragma unroll
      for (int e = 1; e < E_; e++) if (acc[e] > acc[i0]) i0 = e;
      int i1 = -1; float b1 = -3.0e38f;
#pragma unroll
      for (int e = 0; e < E_; e++) if (e != i0 && acc[e] > b1) { b1 = acc[e]; i1 = e; }
      float v0 = acc[i0], v1 = acc[i1];
      float m2 = fmaxf(v0, v1);
      float e0 = expf(v0 - m2), e1 = expf(v1 - m2);
      float p0 = e0 / (e0 + e1), p1 = e1 / (e0 + e1);
      float mx = acc[0];
#pragma unroll
      for (int e = 1; e < E_; e++) mx = fmaxf(mx, acc[e]);
      float se = 0.f;
#pragma unroll
      for (int e = 0; e < E_; e++) se += expf(acc[e] - mx);
      float z = mx + logf(se);
      float inv = 1.f / se;
#pragma unroll
      for (int e = 0; e < E_; e++) lp[wid][e] = expf(acc[e] - mx) * inv;
#pragma unroll
      for (int e = 0; e < E_; e++) lp[wid][8 + e] = (e == i0) ? p0 : ((e == i1) ? p1 : 0.f);
      lp[wid][16] = z * z;
#pragma unroll
      for (int e = 0; e < E_; e++) lc[wid][e] = (e == i0) + (e == i1);
      te[n * 2] = i0; te[n * 2 + 1] = i1;
      prio[n * 2] = v0; prio[n * 2 + 1] = v1;
      tkprob[n * 2] = p0; tkprob[n * 2 + 1] = p1;
      out_topk[n * 2] = (float)i0; out_topk[n * 2 + 1] = (float)i1;
    } else {
      for (int t = 0; t < 17; t++) lp[wid][t] = 0.f;
      for (int e = 0; e < E_; e++) lc[wid][e] = 0;
    }
  }
  __syncthreads();
  int tid = threadIdx.x;
  if (tid < 17)
    partials[(size_t)blockIdx.x * 17 + tid] = lp[0][tid] + lp[1][tid] + lp[2][tid] + lp[3][tid];
  if (tid >= 32 && tid < 40) {
    int e = tid - 32;
    pcounts[(size_t)blockIdx.x * 8 + e] = lc[0][e] + lc[1][e] + lc[2][e] + lc[3][e];
  }
}

// ---------------- stats ----------------
__global__ void stats_k(const float* __restrict__ partials, const int* __restrict__ pcounts,
                        int NB, int* __restrict__ counts, int* __restrict__ starts,
                        int* __restrict__ rows_e, int* __restrict__ ctr,
                        float* __restrict__ aux_out, int N, int C)
{
  __shared__ float ssum[17];
  __shared__ int scnt[8];
  int wave = threadIdx.x >> 6, lane = threadIdx.x & 63;
  for (int v = wave; v < 17; v += 4) {
    float s = 0.f;
    for (int b = lane; b < NB; b += 64) s += partials[(size_t)b * 17 + v];
    s = wred(s);
    if (lane == 0) ssum[v] = s;
  }
  for (int e = wave; e < 8; e += 4) {
    int c = 0;
    for (int b = lane; b < NB; b += 64) c += pcounts[(size_t)b * 8 + e];
    c = wredi(c);
    if (lane == 0) scnt[e] = c;
  }
  __syncthreads();
  if (threadIdx.x == 0) {
    int st = 0, kept = 0;
    float bal = 0.f;
    for (int e = 0; e < E_; e++) {
      counts[e] = scnt[e]; starts[e] = st; st += scnt[e];
      int r = scnt[e] < C ? scnt[e] : C;
      rows_e[e] = r; kept += r;
      bal += (ssum[e] / N) * (ssum[8 + e] / N);
      ctr[e] = 0;
    }
    int NK = N * K_;
    float aux = 0.01f * bal * (float)E_ + 0.001f * (ssum[16] / N)
              + 0.001f * (1.f - (float)kept / (float)NK);
    aux_out[0] = aux;
  }
}

// ---------------- rank/slot assignment ----------------
__global__ void rank_k(const int* __restrict__ te, const float* __restrict__ prio,
                       const int* __restrict__ counts, const int* __restrict__ starts,
                       int* __restrict__ ctr, int* __restrict__ rowmap,
                       int* __restrict__ keep_nk, int NK, int C)
{
  int i = blockIdx.x * 256 + threadIdx.x;
  if (i >= NK) return;
  int e = te[i];
  int cnt = counts[e];
  int pos;
  if (cnt <= C) {
    pos = atomicAdd(&ctr[e], 1);
  } else {
    float p = prio[i]; int r = 0;
    for (int j = 0; j < NK; j++) {
      if (te[j] == e) { float pj = prio[j]; r += (pj > p) || (pj == p && j < i); }
    }
    pos = r;
  }
  int kp = pos < C ? 1 : 0;
  keep_nk[i] = kp;
  if (kp) rowmap[starts[e] + pos] = i;
}

// ---------------- tokens init ----------------
__global__ void tokinit_k(float* __restrict__ tokens, h16* __restrict__ tokh,
                          const float* __restrict__ med, int total)
{
  for (int idx = blockIdx.x * 256 + threadIdx.x; idx < total; idx += gridDim.x * 256) {
    int r = idx % (3 * D_);
    float v = (r >= 2 * D_) ? med[r - 2 * D_] : 0.f;
    tokens[idx] = v; tokh[idx] = (h16)v;
  }
}

// =====================================================================================
// MFMA GEMM: C(M,N)=A(M,K)@B(N,K)^T. 128x128 tile, 4 waves, 4x4 frags of 16x16x32.
// BH=true: fp16 A and B via pipelined mfma_core. BH=false: legacy reg-stage fallback.
// EPI: 0 +bias->C16 ; 1 C32+=acc+bias ; 2 gelu->C16 ; 3 t=acc+C32 ->C32&C16 ; 4 ->C32
// =====================================================================================
template<int EPI, bool BH>
__global__ __launch_bounds__(256, 2) void mgemm_k(
    const h16* __restrict__ A, int lda, const void* __restrict__ Bv,
    const float* __restrict__ bias, float* C32, h16* C16, int M, int N, int K)
{
  __shared__ __align__(16) h16 ls[16384];
  const int tid = threadIdx.x;
  const int lane = tid & 63, wave = tid >> 6;
  const int wm = wave >> 1, wn = wave & 1;
  const int lr = lane & 15, lk = lane >> 4;
  const int m0 = blockIdx.y * 128, n0 = blockIdx.x * 128;

  f32x4 acc[4][4];
#pragma unroll
  for (int i = 0; i < 4; ++i)
#pragma unroll
    for (int j = 0; j < 4; ++j) acc[i][j] = f32x4{0.f, 0.f, 0.f, 0.f};

  if constexpr (BH) {
    const h16* Bh = (const h16*)Bv;
    size_t srow[4];
    const h16* src;
    if (wave < 2) {
#pragma unroll
      for (int j = 0; j < 4; ++j)
        srow[j] = (size_t)(m0 + ((wave & 1) * 4 + j) * 16 + lr) * (size_t)lda;
      src = A;
    } else {
#pragma unroll
      for (int j = 0; j < 4; ++j)
        srow[j] = (size_t)(n0 + ((wave & 1) * 4 + j) * 16 + lr) * (size_t)K;
      src = Bh;
    }
    mfma_core(src, srow, K >> 5, ls, acc, lane, wave);
  } else {
    const float* Bf = (const float*)Bv;
    const int ldsbase = (wave < 2) ? wave * 4096 : 8192 + (wave - 2) * 4096;
    const int koff = (wave & 1) * 32 + lk * 8;
    size_t srow[8];
    if (wave < 2) {
#pragma unroll
      for (int j = 0; j < 8; ++j) srow[j] = (size_t)(m0 + j * 16 + lr) * (size_t)lda;
    } else {
#pragma unroll
      for (int j = 0; j < 8; ++j) srow[j] = (size_t)(n0 + j * 16 + lr) * (size_t)K;
    }
    const int nkt = K >> 6;
    for (int kt = 0; kt < nkt; ++kt) {
      const int kb = kt * 64 + koff;
      __syncthreads();
      if (wave < 2) {
#pragma unroll
        for (int j = 0; j < 8; ++j) gload16(A + srow[j] + kb, &ls[ldsbase + j * 512]);
      } else {
#pragma unroll
        for (int j = 0; j < 8; ++j) {
          float4 u0 = *(const float4*)(Bf + srow[j] + kb);
          float4 u1 = *(const float4*)(Bf + srow[j] + kb + 4);
          *(h8*)&ls[ldsbase + j * 512 + lane * 8] = cvt8(u0, u1, 1.f);
        }
      }
      __syncthreads();
#pragma unroll
      for (int kc = 0; kc < 2; ++kc) {
        h8 af[4], bf[4];
#pragma unroll
        for (int i = 0; i < 4; ++i) af[i] = *(const h8*)&ls[(kc * 8 + wm * 4 + i) * 512 + lane * 8];
#pragma unroll
        for (int j = 0; j < 4; ++j) bf[j] = *(const h8*)&ls[8192 + (kc * 8 + wn * 4 + j) * 512 + lane * 8];
#pragma unroll
        for (int i = 0; i < 4; ++i)
#pragma unroll
          for (int j = 0; j < 4; ++j)
            acc[i][j] = __builtin_amdgcn_mfma_f32_16x16x32_f16(af[i], bf[j], acc[i][j], 0, 0, 0);
      }
    }
  }

#pragma unroll
  for (int i = 0; i < 4; ++i) {
    const int row0 = m0 + (wm * 4 + i) * 16 + lk * 4;
#pragma unroll
    for (int j = 0; j < 4; ++j) {
      const int col = n0 + (wn * 4 + j) * 16 + lr;
      const float bv = (EPI == 0 || EPI == 1) ? bias[col] : 0.f;
#pragma unroll
      for (int r = 0; r < 4; ++r) {
        const size_t o = (size_t)(row0 + r) * N + col;
        const float v = acc[i][j][r];
        if (EPI == 0)      { C16[o] = (h16)(v + bv); }
        else if (EPI == 1) { C32[o] += v + bv; }
        else if (EPI == 2) { C16[o] = (h16)gelu_f(v); }
        else if (EPI == 3) { float t = v + C32[o]; C32[o] = t; C16[o] = (h16)t; }
        else               { C32[o] = v; }
      }
    }
  }
}

// ---------------- expert GEMM1: act = silu(2x Wg^T)*(2x Wu^T), gathered rows ----------------
// B unit u: cg=u>>1 (out colgroup), half=u&1 (0 gate / 1 up). w13h pre-scaled by 2.
template<bool BH>
__global__ __launch_bounds__(256, 2) void egemm1_k(
    const float* __restrict__ x, const h16* __restrict__ xh,
    const float* __restrict__ w13, const h16* __restrict__ w13h,
    const int* __restrict__ rowmap, const int* __restrict__ starts,
    const int* __restrict__ rows_e, h16* __restrict__ acth)
{
  const int e = blockIdx.z;
  const int rows = rows_e[e], st = starts[e];
  const int r0 = blockIdx.y * 128;
  if (r0 >= rows) return;
  const int h0 = blockIdx.x * 64;

  __shared__ __align__(16) h16 ls[16384];
  const int tid = threadIdx.x;
  const int lane = tid & 63, wave = tid >> 6;
  const int wm = wave >> 1, wn = wave & 1;
  const int lr = lane & 15, lk = lane >> 4;

  f32x4 acc[4][4];
#pragma unroll
  for (int i = 0; i < 4; ++i)
#pragma unroll
    for (int j = 0; j < 4; ++j) acc[i][j] = f32x4{0.f, 0.f, 0.f, 0.f};

  if constexpr (BH) {
    size_t srow[4];
    const h16* src;
    if (wave < 2) {
#pragma unroll
      for (int j = 0; j < 4; ++j) {
        int r = r0 + ((wave & 1) * 4 + j) * 16 + lr; if (r >= rows) r = rows - 1;
        srow[j] = (size_t)(rowmap[st + r] >> 1) * D_;
      }
      src = xh;
    } else {
#pragma unroll
      for (int j = 0; j < 4; ++j) {
        int u = (wave & 1) * 4 + j;
        srow[j] = ((size_t)e * 4096 + (size_t)(u & 1) * 2048 + h0 + (u >> 1) * 16 + lr) * D_;
      }
      src = w13h;
    }
    mfma_core(src, srow, D_ / 32, ls, acc, lane, wave);
  } else {
    const int ldsbase = (wave < 2) ? wave * 4096 : 8192 + (wave - 2) * 4096;
    const int koff = (wave & 1) * 32 + lk * 8;
    size_t srow[8];
    if (wave < 2) {
#pragma unroll
      for (int j = 0; j < 8; ++j) {
        int r = r0 + j * 16 + lr; if (r >= rows) r = rows - 1;
        srow[j] = (size_t)(rowmap[st + r] >> 1) * D_;
      }
    } else {
#pragma unroll
      for (int j = 0; j < 8; ++j)
        srow[j] = ((size_t)e * 4096 + (size_t)(j & 1) * 2048 + h0 + (j >> 1) * 16 + lr) * D_;
    }
    for (int kt = 0; kt < D_ / 64; ++kt) {
      const int kb = kt * 64 + koff;
      __syncthreads();
      const float* src = (wave < 2) ? x : w13;
      const float sc = (wave < 2) ? 2.f : 1.f;
#pragma unroll
      for (int j = 0; j < 8; ++j) {
        float4 u0 = *(const float4*)(src + srow[j] + kb);
        float4 u1 = *(const float4*)(src + srow[j] + kb + 4);
        *(h8*)&ls[ldsbase + j * 512 + lane * 8] = cvt8(u0, u1, sc);
      }
      __syncthreads();
#pragma unroll
      for (int kc = 0; kc < 2; ++kc) {
        h8 af[4], bf[4];
#pragma unroll
        for (int i = 0; i < 4; ++i) af[i] = *(const h8*)&ls[(kc * 8 + wm * 4 + i) * 512 + lane * 8];
#pragma unroll
        for (int j = 0; j < 4; ++j) bf[j] = *(const h8*)&ls[8192 + (kc * 8 + wn * 4 + j) * 512 + lane * 8];
#pragma unroll
        for (int i = 0; i < 4; ++i)
#pragma unroll
          for (int j = 0; j < 4; ++j)
            acc[i][j] = __builtin_amdgcn_mfma_f32_16x16x32_f16(af[i], bf[j], acc[i][j], 0, 0, 0);
      }
    }
  }

#pragma unroll
  for (int i = 0; i < 4; ++i) {
    const int rloc = r0 + (wm * 4 + i) * 16 + lk * 4;
#pragma unroll
    for (int jc = 0; jc < 2; ++jc) {
      const int col = h0 + (wn * 2 + jc) * 16 + lr;
#pragma unroll
      for (int r = 0; r < 4; ++r) {
        const int rr = rloc + r;
        if (rr < rows) {
          float g = acc[i][2 * jc][r], u = acc[i][2 * jc + 1][r];
          acth[(size_t)(st + rr) * HFF_ + col] = (h16)(silu_f(g) * u);
        }
      }
    }
  }
}

// ---------------- expert GEMM2: tokens[t,l] = x[t] + act @ w2^T (scatter) ----------------
template<bool BH>
__global__ __launch_bounds__(256, 2) void egemm2_k(
    const h16* __restrict__ acth, const float* __restrict__ w2, const h16* __restrict__ w2h,
    const int* __restrict__ rowmap, const int* __restrict__ starts,
    const int* __restrict__ rows_e, const float* __restrict__ x,
    float* __restrict__ tokens, h16* __restrict__ tokh)
{
  const int e = blockIdx.z;
  const int rows = rows_e[e], st = starts[e];
  const int r0 = blockIdx.y * 128;
  if (r0 >= rows) return;
  const int n0 = blockIdx.x * 128;

  __shared__ __align__(16) h16 ls[16384];
  const int tid = threadIdx.x;
  const int lane = tid & 63, wave = tid >> 6;
  const int wm = wave >> 1, wn = wave & 1;
  const int lr = lane & 15, lk = lane >> 4;

  f32x4 acc[4][4];
#pragma unroll
  for (int i = 0; i < 4; ++i)
#pragma unroll
    for (int j = 0; j < 4; ++j) acc[i][j] = f32x4{0.f, 0.f, 0.f, 0.f};

  if constexpr (BH) {
    size_t srow[4];
    const h16* src;
    if (wave < 2) {
#pragma unroll
      for (int j = 0; j < 4; ++j) {
        int r = r0 + ((wave & 1) * 4 + j) * 16 + lr; if (r >= rows) r = rows - 1;
        srow[j] = (size_t)(st + r) * HFF_;
      }
      src = acth;
    } else {
#pragma unroll
      for (int j = 0; j < 4; ++j)
        srow[j] = ((size_t)e * D_ + n0 + ((wave & 1) * 4 + j) * 16 + lr) * HFF_;
      src = w2h;
    }
    mfma_core(src, srow, HFF_ / 32, ls, acc, lane, wave);
  } else {
    const int ldsbase = (wave < 2) ? wave * 4096 : 8192 + (wave - 2) * 4096;
    const int koff = (wave & 1) * 32 + lk * 8;
    size_t srow[8];
    if (wave < 2) {
#pragma unroll
      for (int j = 0; j < 8; ++j) {
        int r = r0 + j * 16 + lr; if (r >= rows) r = rows - 1;
        srow[j] = (size_t)(st + r) * HFF_;
      }
    } else {
#pragma unroll
      for (int j = 0; j < 8; ++j)
        srow[j] = ((size_t)e * D_ + n0 + j * 16 + lr) * HFF_;
    }
    for (int kt = 0; kt < HFF_ / 64; ++kt) {
      const int kb = kt * 64 + koff;
      __syncthreads();
      if (wave < 2) {
#pragma unroll
        for (int j = 0; j < 8; ++j) gload16(acth + srow[j] + kb, &ls[ldsbase + j * 512]);
      } else {
#pragma unroll
        for (int j = 0; j < 8; ++j) {
          float4 u0 = *(const float4*)(w2 + srow[j] + kb);
          float4 u1 = *(const float4*)(w2 + srow[j] + kb + 4);
          *(h8*)&ls[ldsbase + j * 512 + lane * 8] = cvt8(u0, u1, 1.f);
        }
      }
      __syncthreads();
#pragma unroll
      for (int kc = 0; kc < 2; ++kc) {
        h8 af[4], bf[4];
#pragma unroll
        for (int i = 0; i < 4; ++i) af[i] = *(const h8*)&ls[(kc * 8 + wm * 4 + i) * 512 + lane * 8];
#pragma unroll
        for (int j = 0; j < 4; ++j) bf[j] = *(const h8*)&ls[8192 + (kc * 8 + wn * 4 + j) * 512 + lane * 8];
#pragma unroll
        for (int i = 0; i < 4; ++i)
#pragma unroll
          for (int j = 0; j < 4; ++j)
            acc[i][j] = __builtin_amdgcn_mfma_f32_16x16x32_f16(af[i], bf[j], acc[i][j], 0, 0, 0);
      }
    }
  }

#pragma unroll
  for (int i = 0; i < 4; ++i) {
    const int rloc = r0 + (wm * 4 + i) * 16 + lk * 4;
#pragma unroll
    for (int j = 0; j < 4; ++j) {
      const int col = n0 + (wn * 4 + j) * 16 + lr;
#pragma unroll
      for (int r = 0; r < 4; ++r) {
        const int rr = rloc + r;
        if (rr < rows) {
          int item = rowmap[st + rr];
          int t = item >> 1, l = item & 1;
          size_t o = ((size_t)t * 3 + l) * D_ + col;
          float v = acc[i][j][r] + x[(size_t)t * D_ + col];
          tokens[o] = v; tokh[o] = (h16)v;
        }
      }
    }
  }
}

// ---------------- attention over L=3 tokens, IN-PLACE into q-slots of qkv ----------------
__global__ void attn_k(h16* qkv, const int* __restrict__ keep_nk, int N)
{
  int n = blockIdx.x;
  int h = threadIdx.y, lane = threadIdx.x;
  h16* base = qkv + (size_t)n * 3 * 2304;
  float qr[3][3], kr[3][3], vr[3][3];
#pragma unroll
  for (int l2 = 0; l2 < 3; l2++) {
    const h16* row = base + l2 * 2304 + h * 192;
#pragma unroll
    for (int c = 0; c < 3; c++) {
      qr[l2][c] = (float)row[c * 64 + lane];
      kr[l2][c] = (float)row[768 + c * 64 + lane];
      vr[l2][c] = (float)row[1536 + c * 64 + lane];
    }
  }
  const float scale = 0.07216878364870323f; // 1/sqrt(192)
  float bj0 = keep_nk[n * 2] ? 0.f : -1e9f;
  float bj1 = keep_nk[n * 2 + 1] ? 0.f : -1e9f;
  float a[3][3];
#pragma unroll
  for (int i2 = 0; i2 < 3; i2++) {
    float s0 = wred(qr[i2][0] * kr[0][0] + qr[i2][1] * kr[0][1] + qr[i2][2] * kr[0][2]) * scale + bj0;
    float s1 = wred(qr[i2][0] * kr[1][0] + qr[i2][1] * kr[1][1] + qr[i2][2] * kr[1][2]) * scale + bj1;
    float s2 = wred(qr[i2][0] * kr[2][0] + qr[i2][1] * kr[2][1] + qr[i2][2] * kr[2][2]) * scale;
    float m = fmaxf(s0, fmaxf(s1, s2));
    float e0 = expf(s0 - m), e1 = expf(s1 - m), e2 = expf(s2 - m);
    float inv = 1.f / (e0 + e1 + e2);
    a[i2][0] = e0 * inv; a[i2][1] = e1 * inv; a[i2][2] = e2 * inv;
  }
#pragma unroll
  for (int i2 = 0; i2 < 3; i2++) {
    h16* dst = base + i2 * 2304 + h * 192;
#pragma unroll
    for (int c = 0; c < 3; c++)
      dst[c * 64 + lane] = (h16)(a[i2][0] * vr[0][c] + a[i2][1] * vr[1][c] + a[i2][2] * vr[2][c]);
  }
}

// ---------------- fused RMSNorm: tokens = rms(tokens)*w1 ; nrmh = fp16(rms(tokens')*w2) ------
__global__ void rms12_k(float* tokens, const float* __restrict__ w1,
                        const float* __restrict__ w2, h16* __restrict__ nrmh)
{
  int row = blockIdx.x, tid = threadIdx.x;
  float* s = tokens + (size_t)row * D_;
  float v0 = s[tid], v1 = s[tid + 256], v2 = s[tid + 512];
  __shared__ float redA[4], redB[4];
  float ss = v0 * v0 + v1 * v1 + v2 * v2;
  float wsum = wred(ss);
  if ((tid & 63) == 0) redA[tid >> 6] = wsum;
  __syncthreads();
  float tot = redA[0] + redA[1] + redA[2] + redA[3];
  float r = 1.f / sqrtf(tot * (1.f / 768.f) + 1e-6f);
  float t0 = v0 * r * w1[tid];
  float t1 = v1 * r * w1[tid + 256];
  float t2 = v2 * r * w1[tid + 512];
  float ss2 = t0 * t0 + t1 * t1 + t2 * t2;
  float wsum2 = wred(ss2);
  if ((tid & 63) == 0) redB[tid >> 6] = wsum2;
  __syncthreads();
  float tot2 = redB[0] + redB[1] + redB[2] + redB[3];
  float r2 = 1.f / sqrtf(tot2 * (1.f / 768.f) + 1e-6f);
  s[tid] = t0; s[tid + 256] = t1; s[tid + 512] = t2;
  h16* dd = nrmh + (size_t)row * D_;
  dd[tid]       = (h16)(t0 * r2 * w2[tid]);
  dd[tid + 256] = (h16)(t1 * r2 * w2[tid + 256]);
  dd[tid + 512] = (h16)(t2 * r2 * w2[tid + 512]);
}

// ---------------- final fuse ----------------
__global__ void fuse_k(const float* __restrict__ tokens, const float* __restrict__ tkprob,
                       const int* __restrict__ keep_nk, const float* __restrict__ fw,
                       const float* __restrict__ fb, h16* __restrict__ out)
{
  int n = blockIdx.x; int tid = threadIdx.x;
  const float* t0 = tokens + ((size_t)n * 3 + 0) * D_;
  const float* t1 = tokens + ((size_t)n * 3 + 1) * D_;
  const float* md = tokens + ((size_t)n * 3 + 2) * D_;
  float p = md[tid] * fw[tid] + md[tid + 256] * fw[tid + 256] + md[tid + 512] * fw[tid + 512];
  __shared__ float red[4];
  float wsum = wred(p);
  if ((tid & 63) == 0) red[tid >> 6] = wsum;
  __syncthreads();
  float dot = red[0] + red[1] + red[2] + red[3];
  float g = 1.f / (1.f + expf(-(dot + fb[0])));
  float tp0 = keep_nk[n * 2] ? tkprob[n * 2] : 0.f;
  float tp1 = keep_nk[n * 2 + 1] ? tkprob[n * 2 + 1] : 0.f;
  float den = tp0 + tp1;
  float w0 = den > 0.f ? tp0 / den : 0.f;
  float w1 = den > 0.f ? tp1 / den : 0.f;
  h16* d = out + (size_t)n * D_;
#pragma unroll
  for (int c3 = 0; c3 < 3; c3++) {
    int c = tid + c3 * 256;
    d[c] = (h16)(g * md[c] + (1.f - g) * (w0 * t0[c] + w1 * t1[c]));
  }
}

template<bool BH>
static void run_pipeline(const float* x, const float* gate_w, const float* w13,
                         const float* w2, const float* in_proj_w, const float* in_proj_b,
                         const float* out_w, const float* out_b, const float* norm1_w,
                         const float* norm2_w, const float* ffn_w1, const float* ffn_w2,
                         const float* mediator, const float* fuse_w, const float* fuse_b,
                         const float* o_proj_w,
                         float* partials, int* pcounts, int* counts, int* starts,
                         int* rows_e, int* ctr, int* te, int* keep_nk, int* rowmap,
                         float* prio, float* tkprob, float* tokens, h16* tokh, h16* big,
                         h16* xh, h16* w13h, h16* w2h, h16* inprojh, h16* outwh,
                         h16* ffn1h, h16* ffn2h, h16* oprojh,
                         float* out_fused, float* out_aux, float* out_topk,
                         int N, int C, int NB, int M3, hipStream_t stream)
{
  h16* acth   = big;
  h16* qkvh   = big;
  h16* nrmh   = big;                       // sub0 after qkv dead
  h16* h1h    = big + (size_t)M3 * D_;     // sub1
  h16* fusedh = big;

  if (BH) {
    cvt_k<<<512,  256, 0, stream>>>(x, xh, N * D_, 1.0f);
    cvt_k<<<2048, 256, 0, stream>>>(w13, w13h, E_ * 2 * HFF_ * D_, 2.0f);
    cvt_k<<<2048, 256, 0, stream>>>(w2, w2h, E_ * D_ * HFF_, 1.0f);
    cvt_k<<<256,  256, 0, stream>>>(in_proj_w, inprojh, 3 * D_ * D_, 1.0f);
    cvt_k<<<128,  256, 0, stream>>>(out_w, outwh, D_ * D_, 1.0f);
    cvt_k<<<128,  256, 0, stream>>>(ffn_w1, ffn1h, D_ * D_, 1.0f);
    cvt_k<<<128,  256, 0, stream>>>(ffn_w2, ffn2h, D_ * D_, 1.0f);
    cvt_k<<<128,  256, 0, stream>>>(o_proj_w, oprojh, D_ * D_, 1.0f);
  }

  router_k<<<NB, 256, 0, stream>>>(x, gate_w, partials, pcounts, prio, tkprob, te, out_topk, N);
  stats_k<<<1, 256, 0, stream>>>(partials, pcounts, NB, counts, starts, rows_e, ctr, out_aux, N, C);
  rank_k<<<(N * K_ + 255) / 256, 256, 0, stream>>>(te, prio, counts, starts, ctr, rowmap, keep_nk, N * K_, C);
  tokinit_k<<<2048, 256, 0, stream>>>(tokens, tokh, mediator, M3 * D_);

  int ytil = (C + 127) / 128;
  egemm1_k<BH><<<dim3(HFF_ / 64, ytil, E_), 256, 0, stream>>>(x, xh, w13, w13h, rowmap, starts, rows_e, acth);
  egemm2_k<BH><<<dim3(D_ / 128, ytil, E_), 256, 0, stream>>>(acth, w2, w2h, rowmap, starts, rows_e, x, tokens, tokh);

  const void* inpB  = BH ? (const void*)inprojh : (const void*)in_proj_w;
  const void* outB  = BH ? (const void*)outwh   : (const void*)out_w;
  const void* f1B   = BH ? (const void*)ffn1h   : (const void*)ffn_w1;
  const void* f2B   = BH ? (const void*)ffn2h   : (const void*)ffn_w2;
  const void* opB   = BH ? (const void*)oprojh  : (const void*)o_proj_w;

  for (int step = 0; step < 2; step++) {
    mgemm_k<0, BH><<<dim3(2304 / 128, M3 / 128), 256, 0, stream>>>(tokh, D_, inpB, in_proj_b, nullptr, qkvh, M3, 2304, D_);
    attn_k<<<N, dim3(64, 4), 0, stream>>>(qkvh, keep_nk, N);
    mgemm_k<1, BH><<<dim3(D_ / 128, M3 / 128), 256, 0, stream>>>(qkvh, 2304, outB, out_b, tokens, nullptr, M3, D_, D_);
    rms12_k<<<M3, 256, 0, stream>>>(tokens, norm1_w, norm2_w, nrmh);
    mgemm_k<2, BH><<<dim3(D_ / 128, M3 / 128), 256, 0, stream>>>(nrmh, D_, f1B, nullptr, nullptr, h1h, M3, D_, D_);
    mgemm_k<3, BH><<<dim3(D_ / 128, M3 / 128), 256, 0, stream>>>(h1h, D_, f2B, nullptr, tokens, tokh, M3, D_, D_);
  }

  fuse_k<<<N, 256, 0, stream>>>(tokens, tkprob, keep_nk, fuse_w, fuse_b, fusedh);
  mgemm_k<4, BH><<<dim3(D_ / 128, N / 128), 256, 0, stream>>>(fusedh, D_, opB, nullptr, out_fused, nullptr, N, D_, D_);
}

extern "C" void kernel_launch(void* const* d_in, const int* in_sizes, int n_in,
                              void* d_out, int out_size, void* d_ws, size_t ws_size,
                              hipStream_t stream) {
  const float* x         = (const float*)d_in[0];
  const float* gate_w    = (const float*)d_in[1];
  const float* w13       = (const float*)d_in[2];
  const float* w2        = (const float*)d_in[3];
  const float* in_proj_w = (const float*)d_in[4];
  const float* in_proj_b = (const float*)d_in[5];
  const float* out_w     = (const float*)d_in[6];
  const float* out_b     = (const float*)d_in[7];
  const float* norm1_w   = (const float*)d_in[8];
  const float* norm2_w   = (const float*)d_in[9];
  const float* ffn_w1    = (const float*)d_in[10];
  const float* ffn_w2    = (const float*)d_in[11];
  const float* mediator  = (const float*)d_in[12];
  const float* fuse_w    = (const float*)d_in[13];
  const float* fuse_b    = (const float*)d_in[14];
  const float* o_proj_w  = (const float*)d_in[15];

  const int N = in_sizes[0] / D_;     // 8192
  const int NK = N * K_;
  int capc = (int)ceil((double)NK / E_ * 1.25);
  int C = 1; while (C < capc) C <<= 1; // 4096
  const int NB = (N + 3) / 4;
  const int M3 = N * 3;

  size_t off = 0;
  auto alloc = [&](size_t bytes) -> void* {
    void* r = (char*)d_ws + off;
    off += (bytes + 255) & ~(size_t)255;
    return r;
  };
  float* partials = (float*)alloc(sizeof(float) * (size_t)NB * 17);
  int*   pcounts  = (int*)alloc(sizeof(int) * (size_t)NB * 8);
  int*   counts   = (int*)alloc(sizeof(int) * 8);
  int*   starts   = (int*)alloc(sizeof(int) * 8);
  int*   rows_e   = (int*)alloc(sizeof(int) * 8);
  int*   ctr      = (int*)alloc(sizeof(int) * 8);
  int*   te       = (int*)alloc(sizeof(int) * (size_t)NK);
  int*   keep_nk  = (int*)alloc(sizeof(int) * (size_t)NK);
  int*   rowmap   = (int*)alloc(sizeof(int) * (size_t)NK);
  float* prio     = (float*)alloc(sizeof(float) * (size_t)NK);
  float* tkprob   = (float*)alloc(sizeof(float) * (size_t)NK);
  float* tokens   = (float*)alloc(sizeof(float) * (size_t)M3 * D_);
  h16*   tokh     = (h16*)alloc(sizeof(h16) * (size_t)M3 * D_);
  h16*   big      = (h16*)alloc(sizeof(h16) * (size_t)M3 * 2304);
  h16* xh      = (h16*)alloc(sizeof(h16) * (size_t)N * D_);
  h16* w13h    = (h16*)alloc(sizeof(h16) * (size_t)E_ * 2 * HFF_ * D_);
  h16* w2h     = (h16*)alloc(sizeof(h16) * (size_t)E_ * D_ * HFF_);
  h16* inprojh = (h16*)alloc(sizeof(h16) * (size_t)3 * D_ * D_);
  h16* outwh   = (h16*)alloc(sizeof(h16) * (size_t)D_ * D_);
  h16* ffn1h   = (h16*)alloc(sizeof(h16) * (size_t)D_ * D_);
  h16* ffn2h   = (h16*)alloc(sizeof(h16) * (size_t)D_ * D_);
  h16* oprojh  = (h16*)alloc(sizeof(h16) * (size_t)D_ * D_);
  const bool use_bh = (off <= ws_size);

  float* out_fused = (float*)d_out;
  float* out_aux   = out_fused + (size_t)N * D_;
  float* out_topk  = out_aux + 1;

  if (use_bh)
    run_pipeline<true>(x, gate_w, w13, w2, in_proj_w, in_proj_b, out_w, out_b, norm1_w,
                       norm2_w, ffn_w1, ffn_w2, mediator, fuse_w, fuse_b, o_proj_w,
                       partials, pcounts, counts, starts, rows_e, ctr, te, keep_nk, rowmap,
                       prio, tkprob, tokens, tokh, big, xh, w13h, w2h, inprojh, outwh,
                       ffn1h, ffn2h, oprojh, out_fused, out_aux, out_topk,
                       N, C, NB, M3, stream);
  else
    run_pipeline<false>(x, gate_w, w13, w2, in_proj_w, in_proj_b, out_w, out_b, norm1_w,
                        norm2_w, ffn_w1, ffn_w2, mediator, fuse_w, fuse_b, o_proj_w,
                        partials, pcounts, counts, starts, rows_e, ctr, te, keep_nk, rowmap,
                        prio, tkprob, tokens, tokh, big, xh, w13h, w2h, inprojh, outwh,
                        ffn1h, ffn2h, oprojh, out_fused, out_aux, out_topk,
                        N, C, NB, M3, stream);
}